// Round 1
// baseline (1436.355 us; speedup 1.0000x reference)
//
#include <hip/hip_runtime.h>

// SGAHead: B=8, C=256, H=W=128
#define HW_   16384
#define CHW_  4194304
constexpr int Cc   = 256;
constexpr int Hd   = 128;
constexpr int Wd   = 128;
constexpr int Bd   = 8;
constexpr long NT  = 33554432L; // B*C*H*W

// ---------------- projection: Out[b,o,p] = bias[o] + sum_c W[o,c]*X[b,c,p] ----------------
__global__ __launch_bounds__(256) void proj_kernel(const float* __restrict__ X,
    const float* __restrict__ Wm, const float* __restrict__ bias, float* __restrict__ Out) {
  int b  = blockIdx.z;
  int o0 = blockIdx.y * 64;
  int p0 = blockIdx.x * 64;
  const float* Xb = X + (long)b * CHW_;
  float* Ob = Out + (long)b * CHW_;
  __shared__ float Ws[32][68];   // Ws[cc][oo]
  __shared__ float Xs[32][64];   // Xs[cc][pp]
  int t  = threadIdx.x;
  int tx = t & 15, ty = t >> 4;
  float acc[4][4] = {{0.f,0.f,0.f,0.f},{0.f,0.f,0.f,0.f},{0.f,0.f,0.f,0.f},{0.f,0.f,0.f,0.f}};
  for (int c0 = 0; c0 < Cc; c0 += 32) {
    {
      int oo = t >> 2, cc = (t & 3) << 3;
      const float4* g = (const float4*)(Wm + (long)(o0 + oo) * Cc + c0 + cc);
      float4 w0 = g[0], w1 = g[1];
      Ws[cc+0][oo] = w0.x; Ws[cc+1][oo] = w0.y; Ws[cc+2][oo] = w0.z; Ws[cc+3][oo] = w0.w;
      Ws[cc+4][oo] = w1.x; Ws[cc+5][oo] = w1.y; Ws[cc+6][oo] = w1.z; Ws[cc+7][oo] = w1.w;
    }
    {
      int cc = t >> 3, pp = (t & 7) << 3;
      const float4* g = (const float4*)(Xb + (long)(c0 + cc) * HW_ + p0 + pp);
      float4 x0 = g[0], x1 = g[1];
      *(float4*)&Xs[cc][pp]   = x0;
      *(float4*)&Xs[cc][pp+4] = x1;
    }
    __syncthreads();
    #pragma unroll
    for (int kk = 0; kk < 32; kk++) {
      float4 av = *(const float4*)&Ws[kk][ty*4];
      float4 bv = *(const float4*)&Xs[kk][tx*4];
      float a[4]  = {av.x, av.y, av.z, av.w};
      float bb[4] = {bv.x, bv.y, bv.z, bv.w};
      #pragma unroll
      for (int i = 0; i < 4; i++)
        #pragma unroll
        for (int j = 0; j < 4; j++)
          acc[i][j] = fmaf(a[i], bb[j], acc[i][j]);
    }
    __syncthreads();
  }
  #pragma unroll
  for (int i = 0; i < 4; i++) {
    int o = o0 + ty*4 + i;
    float bi = bias[o];
    float4 r;
    r.x = acc[i][0] + bi; r.y = acc[i][1] + bi; r.z = acc[i][2] + bi; r.w = acc[i][3] + bi;
    *(float4*)(Ob + (long)o * HW_ + p0 + tx*4) = r;
  }
}

// ---------------- H<->W transpose: dst[b,c,w,h] = src[b,c,h,w] ----------------
__global__ __launch_bounds__(256) void transpose_hw_kernel(const float* __restrict__ src,
                                                           float* __restrict__ dst) {
  int bc = blockIdx.z;
  int h0 = blockIdx.x * 32, w0 = blockIdx.y * 32;
  long base = (long)bc * HW_;
  __shared__ float tile[32][33];
  int tx = threadIdx.x, ty = threadIdx.y; // 32 x 8
  #pragma unroll
  for (int r = 0; r < 4; r++) {
    int hh = ty + r*8;
    tile[hh][tx] = src[base + (long)(h0+hh)*Wd + w0 + tx];
  }
  __syncthreads();
  #pragma unroll
  for (int r = 0; r < 4; r++) {
    int ww = ty + r*8;
    dst[base + (long)(w0+ww)*Hd + h0 + tx] = tile[tx][ww];
  }
}

// ---------------- energy: E[m,j] = sum_c A[c*HW+m] * B[c*HW+j], slice base per blockIdx.x ----
// slice s: base = (s>>7)*CHW + (s&127)*128 ; output E at Ef + s*16384, row stride 128
__global__ __launch_bounds__(256) void energy_kernel(const float* __restrict__ Qf,
    const float* __restrict__ Kf, float* __restrict__ Ef) {
  int s = blockIdx.x;
  long sb = (long)(s >> 7) * CHW_ + (long)(s & 127) * 128;
  const float* A  = Qf + sb;
  const float* Bm = Kf + sb;
  float* E = Ef + (long)s * 16384;
  __shared__ float As[32][128];
  __shared__ float Bs[32][128];
  int t  = threadIdx.x;
  int tx = t & 15, ty = t >> 4;
  float acc[8][8];
  #pragma unroll
  for (int i = 0; i < 8; i++)
    #pragma unroll
    for (int j = 0; j < 8; j++) acc[i][j] = 0.f;
  for (int c0 = 0; c0 < Cc; c0 += 32) {
    int cc = t >> 3, mm = (t & 7) << 4;
    {
      const float4* g = (const float4*)(A + (long)(c0+cc)*HW_ + mm);
      float4 v0=g[0], v1=g[1], v2=g[2], v3=g[3];
      *(float4*)&As[cc][mm]    = v0; *(float4*)&As[cc][mm+4]  = v1;
      *(float4*)&As[cc][mm+8]  = v2; *(float4*)&As[cc][mm+12] = v3;
    }
    {
      const float4* g = (const float4*)(Bm + (long)(c0+cc)*HW_ + mm);
      float4 v0=g[0], v1=g[1], v2=g[2], v3=g[3];
      *(float4*)&Bs[cc][mm]    = v0; *(float4*)&Bs[cc][mm+4]  = v1;
      *(float4*)&Bs[cc][mm+8]  = v2; *(float4*)&Bs[cc][mm+12] = v3;
    }
    __syncthreads();
    #pragma unroll
    for (int kk = 0; kk < 32; kk++) {
      float4 a0 = *(const float4*)&As[kk][ty*8];
      float4 a1 = *(const float4*)&As[kk][ty*8+4];
      float4 b0 = *(const float4*)&Bs[kk][tx*8];
      float4 b1 = *(const float4*)&Bs[kk][tx*8+4];
      float a[8]  = {a0.x,a0.y,a0.z,a0.w,a1.x,a1.y,a1.z,a1.w};
      float bb[8] = {b0.x,b0.y,b0.z,b0.w,b1.x,b1.y,b1.z,b1.w};
      #pragma unroll
      for (int i = 0; i < 8; i++)
        #pragma unroll
        for (int j = 0; j < 8; j++)
          acc[i][j] = fmaf(a[i], bb[j], acc[i][j]);
    }
    __syncthreads();
  }
  #pragma unroll
  for (int i = 0; i < 8; i++) {
    long rb = (long)(ty*8+i)*128 + tx*8;
    *(float4*)(E + rb)     = make_float4(acc[i][0],acc[i][1],acc[i][2],acc[i][3]);
    *(float4*)(E + rb + 4) = make_float4(acc[i][4],acc[i][5],acc[i][6],acc[i][7]);
  }
}

// ---------------- softmax over concat(attH_row[128], attW_row[128]), in place -------------
__global__ __launch_bounds__(256) void softmax_kernel(float* __restrict__ attH,
                                                      float* __restrict__ attW) {
  int wid  = threadIdx.x >> 6;
  int lane = threadIdx.x & 63;
  long r = (long)blockIdx.x * 4 + wid;         // row = ((b*H+h)*W + w)
  int b = (int)(r >> 14);
  int h = (int)((r >> 7) & 127);
  int w = (int)(r & 127);
  float* rowH = attH + ((long)(b*Wd + w)*Hd + h)*Hd;
  float* rowW = attW + r * 128;
  float x0 = rowH[lane], x1 = rowH[64+lane], x2 = rowW[lane], x3 = rowW[64+lane];
  float m = fmaxf(fmaxf(x0,x1), fmaxf(x2,x3));
  #pragma unroll
  for (int off = 32; off; off >>= 1) m = fmaxf(m, __shfl_xor(m, off, 64));
  float e0 = expf(x0-m), e1 = expf(x1-m), e2 = expf(x2-m), e3 = expf(x3-m);
  float ssum = e0+e1+e2+e3;
  #pragma unroll
  for (int off = 32; off; off >>= 1) ssum += __shfl_xor(ssum, off, 64);
  float inv = 1.0f / ssum;
  rowH[lane] = e0*inv; rowH[64+lane] = e1*inv;
  rowW[lane] = e2*inv; rowW[64+lane] = e3*inv;
}

// ---------------- AV: O[c,m] = scale * sum_j V[c*HW+j] * A[m*128+j] (+ mask) --------------
__global__ __launch_bounds__(256) void av_kernel(const float* __restrict__ Vf,
    const float* __restrict__ Att, const float* __restrict__ Maskf,
    float* __restrict__ Outf, const float* __restrict__ gammap) {
  int s  = blockIdx.x;
  int c0 = blockIdx.y << 7;
  long sb = (long)(s >> 7) * CHW_ + (long)(s & 127) * 128;
  const float* V = Vf + sb;
  const float* A = Att + (long)s * 16384;
  float gamma = gammap[0];
  __shared__ float Vl[32][128];
  __shared__ float Bl[32][128];
  int t  = threadIdx.x;
  int tx = t & 15, ty = t >> 4;
  float acc[8][8];
  #pragma unroll
  for (int i = 0; i < 8; i++)
    #pragma unroll
    for (int j = 0; j < 8; j++) acc[i][j] = 0.f;
  for (int j0 = 0; j0 < 128; j0 += 32) {
    int cm = t >> 1, jj = (t & 1) << 4;
    {
      const float4* g = (const float4*)(V + (long)(c0+cm)*HW_ + j0 + jj);
      #pragma unroll
      for (int u = 0; u < 4; u++) {
        float4 x = g[u];
        Vl[jj+u*4+0][cm] = x.x; Vl[jj+u*4+1][cm] = x.y;
        Vl[jj+u*4+2][cm] = x.z; Vl[jj+u*4+3][cm] = x.w;
      }
    }
    {
      const float4* g = (const float4*)(A + (long)cm*128 + j0 + jj);
      #pragma unroll
      for (int u = 0; u < 4; u++) {
        float4 x = g[u];
        Bl[jj+u*4+0][cm] = x.x; Bl[jj+u*4+1][cm] = x.y;
        Bl[jj+u*4+2][cm] = x.z; Bl[jj+u*4+3][cm] = x.w;
      }
    }
    __syncthreads();
    #pragma unroll
    for (int kk = 0; kk < 32; kk++) {
      float4 a0 = *(const float4*)&Vl[kk][ty*8];
      float4 a1 = *(const float4*)&Vl[kk][ty*8+4];
      float4 b0 = *(const float4*)&Bl[kk][tx*8];
      float4 b1 = *(const float4*)&Bl[kk][tx*8+4];
      float a[8]  = {a0.x,a0.y,a0.z,a0.w,a1.x,a1.y,a1.z,a1.w};
      float bb[8] = {b0.x,b0.y,b0.z,b0.w,b1.x,b1.y,b1.z,b1.w};
      #pragma unroll
      for (int i = 0; i < 8; i++)
        #pragma unroll
        for (int j = 0; j < 8; j++)
          acc[i][j] = fmaf(a[i], bb[j], acc[i][j]);
    }
    __syncthreads();
  }
  #pragma unroll
  for (int i = 0; i < 8; i++) {
    long ob = sb + (long)(c0 + ty*8 + i) * HW_ + tx*8;
    float4 r0, r1;
    r0.x = gamma*acc[i][0]; r0.y = gamma*acc[i][1]; r0.z = gamma*acc[i][2]; r0.w = gamma*acc[i][3];
    r1.x = gamma*acc[i][4]; r1.y = gamma*acc[i][5]; r1.z = gamma*acc[i][6]; r1.w = gamma*acc[i][7];
    if (Maskf) {
      float4 m0 = *(const float4*)(Maskf + ob);
      float4 m1 = *(const float4*)(Maskf + ob + 4);
      r0.x += m0.x; r0.y += m0.y; r0.z += m0.z; r0.w += m0.w;
      r1.x += m1.x; r1.y += m1.y; r1.z += m1.z; r1.w += m1.w;
    }
    *(float4*)(Outf + ob)     = r0;
    *(float4*)(Outf + ob + 4) = r1;
  }
}

// ---------------- merge: out[b,c,h,w] += tmp[b,c,w,h] (tmp already scaled) ----------------
__global__ __launch_bounds__(256) void merge_kernel(const float* __restrict__ tmp,
                                                    float* __restrict__ out) {
  int bc = blockIdx.z;
  int h0 = blockIdx.x * 32, w0 = blockIdx.y * 32;
  long base = (long)bc * HW_;
  __shared__ float tile[32][33];
  int tx = threadIdx.x, ty = threadIdx.y; // 32 x 8
  #pragma unroll
  for (int r = 0; r < 4; r++) {
    int ww = ty + r*8;
    tile[ww][tx] = tmp[base + (long)(w0+ww)*Hd + h0 + tx];
  }
  __syncthreads();
  #pragma unroll
  for (int r = 0; r < 4; r++) {
    int hh = ty + r*8;
    long o = base + (long)(h0+hh)*Wd + w0 + tx;
    out[o] += tile[tx][hh];
  }
}

extern "C" void kernel_launch(void* const* d_in, const int* in_sizes, int n_in,
                              void* d_out, int out_size, void* d_ws, size_t ws_size,
                              hipStream_t stream) {
  const float* edge  = (const float*)d_in[0];
  const float* mask  = (const float*)d_in[1];
  const float* Wq    = (const float*)d_in[2];
  const float* bq    = (const float*)d_in[3];
  const float* Wk    = (const float*)d_in[4];
  const float* bk    = (const float*)d_in[5];
  const float* Wv    = (const float*)d_in[6];
  const float* bv    = (const float*)d_in[7];
  const float* gamma = (const float*)d_in[8];

  float* out  = (float*)d_out;
  float* attH = out + NT;            // B*W*H*H = 16777216
  float* attW = attH + 16777216L;    // B*H*W*W = 16777216

  float* S0 = (float*)d_ws;          // q      -> later vt
  float* S1 = S0 + NT;               // k      -> later tmp (gamma*out_H, transposed)
  float* S2 = S1 + NT;               // v
  float* S3 = S2 + NT;               // qt
  float* S4 = S3 + NT;               // kt

  dim3 pb(256), pg(HW_/64, Cc/64, Bd);          // proj
  dim3 tb(32, 8), tg(4, 4, Bd*Cc);              // transpose / merge

  proj_kernel<<<pg, pb, 0, stream>>>(edge, Wq, bq, S0);
  proj_kernel<<<pg, pb, 0, stream>>>(edge, Wk, bk, S1);
  proj_kernel<<<pg, pb, 0, stream>>>(mask, Wv, bv, S2);

  transpose_hw_kernel<<<tg, tb, 0, stream>>>(S0, S3);
  transpose_hw_kernel<<<tg, tb, 0, stream>>>(S1, S4);

  energy_kernel<<<dim3(1024), 256, 0, stream>>>(S0, S1, attW); // energy_W (natural)
  energy_kernel<<<dim3(1024), 256, 0, stream>>>(S3, S4, attH); // energy_H (transposed)

  softmax_kernel<<<dim3(32768), 256, 0, stream>>>(attH, attW);

  av_kernel<<<dim3(1024, 2), 256, 0, stream>>>(S2, attW, mask, out, gamma);   // gamma*out_W + mask
  transpose_hw_kernel<<<tg, tb, 0, stream>>>(S2, S0);                         // vt
  av_kernel<<<dim3(1024, 2), 256, 0, stream>>>(S0, attH, nullptr, S1, gamma); // gamma*out_H (transposed)
  merge_kernel<<<tg, tb, 0, stream>>>(S1, out);
}

// Round 2
// 894.815 us; speedup vs baseline: 1.6052x; 1.6052x over previous
//
#include <hip/hip_runtime.h>

typedef unsigned short u16;
typedef unsigned int   u32;
typedef __attribute__((ext_vector_type(8))) short short8;
typedef __attribute__((ext_vector_type(4))) float f32x4;

#define HW_   16384
constexpr long CHW_ = 4194304L;
constexpr long NT   = 33554432L; // B*C*H*W

#define GLDS(g, l) __builtin_amdgcn_global_load_lds( \
    (const __attribute__((address_space(1))) void*)(g), \
    (__attribute__((address_space(3))) void*)(l), 16, 0, 0)

__device__ inline u16 f2bf(float x){ u32 u = __float_as_uint(x); u += 0x7fff + ((u>>16)&1); return (u16)(u>>16); }
__device__ inline float bf2f(u16 h){ return __uint_as_float(((u32)h)<<16); }

// swizzled LDS tile: 128 rows x 8 chunks of 16B (8 bf16). elem(row r, chunk c) at
// ushort index r*64 + ((c ^ (r&7))<<3). chunk c = tensor(c>>2)*4 + khi(c&3).
__device__ inline const short8* frg(const u16* T, int r, int c){
  return (const short8*)(T + r*64 + ((c ^ (r&7))<<3));
}

// MODE 0: proj q/k (split, bias by col, split-bf16 out [b][p][256])
// MODE 1: energy   (split, fp32 out att slice, dirH picks row stride)
// MODE 2: proj v   (plain, bias by row, bf16 out [b][c][p])
// MODE 3: av       (plain, gamma*acc (+mask) fp32 out rows stride HW)
template<int MODE, bool SPLIT>
__global__ __launch_bounds__(256) void gemm_nt(
    const u16* __restrict__ Ah, const u16* __restrict__ Al,
    const u16* __restrict__ Bh, const u16* __restrict__ Bl,
    const float* __restrict__ bias, const float* __restrict__ maskp,
    const float* __restrict__ gammap,
    float* __restrict__ outF, u16* __restrict__ outH, u16* __restrict__ outL,
    int dirH)
{
  __shared__ __align__(16) u16 smem[SPLIT ? 16384 : 8192];
  u16* T1 = smem;
  u16* T2 = SPLIT ? (smem + 8192) : smem;

  const int t    = threadIdx.x;
  const int lane = t & 63;
  const int wid  = t >> 6;
  const int wr   = (wid >> 1) << 6;
  const int wc   = (wid & 1) << 6;

  long abase, bbase, ars, brs;
  int b = 0, m0 = 0, n0 = 0, xx = 0, s = 0, ct = 0;
  constexpr int K = (MODE == 3) ? 128 : 256;

  if constexpr (MODE == 0) {
    b = blockIdx.z; m0 = blockIdx.x << 7; n0 = blockIdx.y << 7;
    abase = ((long)b * HW_ + m0) * 256; ars = 256;
    bbase = (long)n0 * 256;             brs = 256;
  } else if constexpr (MODE == 1) {
    s = blockIdx.x; b = s >> 7; xx = s & 127;
    abase = dirH ? ((long)b * HW_ + xx) * 256 : ((long)b * HW_ + (long)xx * 128) * 256;
    ars   = dirH ? 32768 : 256;
    bbase = abase; brs = ars;
  } else if constexpr (MODE == 2) {
    b = blockIdx.z; m0 = blockIdx.y << 7; n0 = blockIdx.x << 7;
    abase = (long)m0 * 256;             ars = 256;
    bbase = ((long)b * HW_ + n0) * 256; brs = 256;
  } else {
    s = blockIdx.x; ct = blockIdx.y; b = s >> 7; xx = s & 127;
    abase = ((long)b * 256 + (long)(ct << 7)) * HW_ + (long)xx * 128; ars = HW_;
    bbase = (long)s * HW_; brs = 128;
  }

  const u16* pA0 = Ah + abase;
  const u16* pA1 = SPLIT ? (Al + abase) : (Bh + bbase);
  const long rsA1 = SPLIT ? ars : brs;
  const u16* pB0 = SPLIT ? (Bh + bbase) : nullptr;
  const u16* pB1 = SPLIT ? (Bl + bbase) : nullptr;

  f32x4 acc[4][4];
  for (int i = 0; i < 4; i++)
    for (int j = 0; j < 4; j++)
      acc[i][j] = (f32x4){0.f, 0.f, 0.f, 0.f};

  // stage one combined tile: 128 rows x (tensor0 64B | tensor1 64B), source-side swizzle
  auto stageC = [&](u16* T, const u16* P0, long rs0, const u16* P1, long rs1) {
    #pragma unroll
    for (int i = 0; i < 4; i++) {
      int r = (i << 5) + (t >> 3);
      int c = (t & 7) ^ (r & 7);
      const u16* g = (c < 4 ? P0 + (long)r * rs0 : P1 + (long)r * rs1) + ((c & 3) << 3);
      u16* l = T + (i << 11) + ((t >> 6) << 9);
      GLDS(g, l);
    }
  };

  const int khi = lane >> 4;
  const int rl  = lane & 15;

  for (int k0 = 0; k0 < K; k0 += 32) {
    stageC(T1, pA0, ars, pA1, rsA1);
    if constexpr (SPLIT) stageC(T2, pB0, brs, pB1, brs);
    __syncthreads();

    short8 bfr[4], bfl[4];
    #pragma unroll
    for (int fn = 0; fn < 4; fn++) {
      int rr = wc + fn * 16 + rl;
      if constexpr (SPLIT) {
        bfr[fn] = *frg(T2, rr, khi);
        bfl[fn] = *frg(T2, rr, 4 + khi);
      } else {
        bfr[fn] = *frg(T1, rr, 4 + khi);
      }
    }
    #pragma unroll
    for (int fm = 0; fm < 4; fm++) {
      int ra = wr + fm * 16 + rl;
      short8 ah = *frg(T1, ra, khi);
      short8 al;
      if constexpr (SPLIT) al = *frg(T1, ra, 4 + khi);
      #pragma unroll
      for (int fn = 0; fn < 4; fn++) {
        acc[fm][fn] = __builtin_amdgcn_mfma_f32_16x16x32_bf16(ah, bfr[fn], acc[fm][fn], 0, 0, 0);
        if constexpr (SPLIT) {
          acc[fm][fn] = __builtin_amdgcn_mfma_f32_16x16x32_bf16(ah, bfl[fn], acc[fm][fn], 0, 0, 0);
          acc[fm][fn] = __builtin_amdgcn_mfma_f32_16x16x32_bf16(al, bfr[fn], acc[fm][fn], 0, 0, 0);
        }
      }
    }
    pA0 += 32; pA1 += 32;
    if constexpr (SPLIT) { pB0 += 32; pB1 += 32; }
    __syncthreads();
  }

  float gma = 0.f;
  if constexpr (MODE == 3) gma = gammap[0];

  #pragma unroll
  for (int fm = 0; fm < 4; fm++) {
    #pragma unroll
    for (int fn = 0; fn < 4; fn++) {
      #pragma unroll
      for (int r = 0; r < 4; r++) {
        int lr = wr + fm * 16 + ((lane >> 4) << 2) + r;
        int lc = wc + fn * 16 + (lane & 15);
        float v = acc[fm][fn][r];
        if constexpr (MODE == 0) {
          v += bias[n0 + lc];
          long idx = ((long)b * HW_ + m0 + lr) * 256 + n0 + lc;
          u16 h = f2bf(v);
          outH[idx] = h;
          outL[idx] = f2bf(v - bf2f(h));
        } else if constexpr (MODE == 1) {
          outF[(long)s * HW_ + (long)lr * 128 + lc] = v;
        } else if constexpr (MODE == 2) {
          v += bias[m0 + lr];
          outH[((long)b * 256 + m0 + lr) * HW_ + n0 + lc] = f2bf(v);
        } else {
          long off = ((long)b * 256 + (long)(ct << 7) + lr) * HW_ + (long)xx * 128 + lc;
          float r2 = gma * v;
          if (maskp) r2 += maskp[off];
          outF[off] = r2;
        }
      }
    }
  }
}

// ---------------- fp32 [c][p] -> bf16 (hi[,lo]) [p][c] per batch ----------------
template<bool SPLIT>
__global__ __launch_bounds__(256) void split_transpose(const float* __restrict__ src,
    u16* __restrict__ hi, u16* __restrict__ lo)
{
  int b = blockIdx.z, c0 = blockIdx.y << 5, p0 = blockIdx.x << 5;
  __shared__ float tile[32][33];
  int tx = threadIdx.x, ty = threadIdx.y;
  const float* S = src + (long)b * CHW_;
  #pragma unroll
  for (int r = 0; r < 4; r++)
    tile[ty + (r << 3)][tx] = S[(long)(c0 + ty + (r << 3)) * HW_ + p0 + tx];
  __syncthreads();
  #pragma unroll
  for (int r = 0; r < 4; r++) {
    int pp = ty + (r << 3);
    float x = tile[tx][pp];
    long idx = ((long)b * HW_ + p0 + pp) * 256 + c0 + tx;
    u16 h = f2bf(x);
    hi[idx] = h;
    if (SPLIT) lo[idx] = f2bf(x - bf2f(h));
  }
}

// ---------------- weight split ----------------
__global__ __launch_bounds__(256) void wsplit(const float* __restrict__ Wq,
    const float* __restrict__ Wk, const float* __restrict__ Wv,
    u16* qh, u16* ql, u16* kh, u16* kl, u16* vh)
{
  int i = blockIdx.x * 256 + threadIdx.x;
  float q = Wq[i]; u16 a = f2bf(q); qh[i] = a; ql[i] = f2bf(q - bf2f(a));
  float k = Wk[i]; u16 c = f2bf(k); kh[i] = c; kl[i] = f2bf(k - bf2f(c));
  vh[i] = f2bf(Wv[i]);
}

// ---------------- bf16 H<->W transpose: dst[bc][w*128+h] = src[bc][h*128+w] ----------------
__global__ __launch_bounds__(256) void transpose_hw_bf16(const u16* __restrict__ src,
                                                         u16* __restrict__ dst)
{
  int bc = blockIdx.z;
  int h0 = blockIdx.x << 5, w0 = blockIdx.y << 5;
  long base = (long)bc * HW_;
  __shared__ u16 tile[32][34];
  int tx = threadIdx.x, ty = threadIdx.y;
  #pragma unroll
  for (int r = 0; r < 4; r++)
    tile[ty + (r << 3)][tx] = src[base + (long)(h0 + ty + (r << 3)) * 128 + w0 + tx];
  __syncthreads();
  #pragma unroll
  for (int r = 0; r < 4; r++) {
    int ww = ty + (r << 3);
    dst[base + (long)(w0 + ww) * 128 + h0 + tx] = tile[tx][ww];
  }
}

// ---------------- softmax over concat(rowH[128], rowW[128]) + bf16 copies ----------------
__global__ __launch_bounds__(256) void softmax_kernel(float* __restrict__ attH,
    float* __restrict__ attW, u16* __restrict__ aHb, u16* __restrict__ aWb)
{
  int wid  = threadIdx.x >> 6;
  int lane = threadIdx.x & 63;
  long r = (long)blockIdx.x * 4 + wid;           // (b,h,w)
  int b = (int)(r >> 14);
  int h = (int)((r >> 7) & 127);
  int w = (int)(r & 127);
  long baseH = ((long)(b * 128 + w) * 128 + h) * 128;
  long baseW = r * 128;
  float* rowH = attH + baseH;
  float* rowW = attW + baseW;
  float x0 = rowH[lane], x1 = rowH[64 + lane], x2 = rowW[lane], x3 = rowW[64 + lane];
  float m = fmaxf(fmaxf(x0, x1), fmaxf(x2, x3));
  #pragma unroll
  for (int off = 32; off; off >>= 1) m = fmaxf(m, __shfl_xor(m, off, 64));
  float e0 = expf(x0 - m), e1 = expf(x1 - m), e2 = expf(x2 - m), e3 = expf(x3 - m);
  float ssum = e0 + e1 + e2 + e3;
  #pragma unroll
  for (int off = 32; off; off >>= 1) ssum += __shfl_xor(ssum, off, 64);
  float inv = 1.0f / ssum;
  float p0 = e0 * inv, p1 = e1 * inv, p2 = e2 * inv, p3 = e3 * inv;
  rowH[lane] = p0; rowH[64 + lane] = p1;
  rowW[lane] = p2; rowW[64 + lane] = p3;
  aHb[baseH + lane] = f2bf(p0); aHb[baseH + 64 + lane] = f2bf(p1);
  aWb[baseW + lane] = f2bf(p2); aWb[baseW + 64 + lane] = f2bf(p3);
}

// ---------------- merge: out[b,c,h,w] += tmp[b,c,w,h] ----------------
__global__ __launch_bounds__(256) void merge_kernel(const float* __restrict__ tmp,
                                                    float* __restrict__ out)
{
  int bc = blockIdx.z;
  int h0 = blockIdx.x << 5, w0 = blockIdx.y << 5;
  long base = (long)bc * HW_;
  __shared__ float tile[32][33];
  int tx = threadIdx.x, ty = threadIdx.y;
  #pragma unroll
  for (int r = 0; r < 4; r++) {
    int ww = ty + (r << 3);
    tile[ww][tx] = tmp[base + (long)(w0 + ww) * 128 + h0 + tx];
  }
  __syncthreads();
  #pragma unroll
  for (int r = 0; r < 4; r++) {
    int hh = ty + (r << 3);
    long o = base + (long)(h0 + hh) * 128 + w0 + tx;
    out[o] += tile[tx][hh];
  }
}

extern "C" void kernel_launch(void* const* d_in, const int* in_sizes, int n_in,
                              void* d_out, int out_size, void* d_ws, size_t ws_size,
                              hipStream_t stream) {
  const float* edge  = (const float*)d_in[0];
  const float* mask  = (const float*)d_in[1];
  const float* Wq    = (const float*)d_in[2];
  const float* bq    = (const float*)d_in[3];
  const float* Wk    = (const float*)d_in[4];
  const float* bk    = (const float*)d_in[5];
  const float* Wv    = (const float*)d_in[6];
  const float* bv    = (const float*)d_in[7];
  const float* gamma = (const float*)d_in[8];

  float* out  = (float*)d_out;
  float* attH = out + NT;            // B*W*H*H
  float* attW = attH + 16777216L;    // B*H*W*W

  char* W = (char*)d_ws;
  const long SLOT = 67108864L;       // 64 MiB
  u16* Xth = (u16*)(W + 0 * SLOT);
  u16* Xtl = (u16*)(W + 1 * SLOT);
  u16* Mt  = (u16*)(W + 2 * SLOT);
  u16* Qh  = (u16*)(W + 3 * SLOT);
  u16* Ql  = (u16*)(W + 4 * SLOT);
  u16* Kh  = (u16*)(W + 5 * SLOT);
  u16* Kl  = (u16*)(W + 6 * SLOT);
  u16* Vb  = (u16*)(W + 7 * SLOT);
  u16* Vtb = (u16*)(W + 0 * SLOT);              // reuse Xth (dead after projections)
  u16* aWb = (u16*)(W + 1 * SLOT);              // reuse Xtl (32 MiB)
  u16* aHb = (u16*)(W + 1 * SLOT + 33554432L);  // (32 MiB)
  float* tmp = (float*)(W + 3 * SLOT);          // reuse Qh/Ql (128 MiB, dead after energy)
  u16* Wqh = (u16*)(W + 8 * SLOT);
  u16* Wql = Wqh + 65536;
  u16* Wkh = Wql + 65536;
  u16* Wkl = Wkh + 65536;
  u16* Wvh = Wkl + 65536;

  dim3 tb(32, 8);

  wsplit<<<256, 256, 0, stream>>>(Wq, Wk, Wv, Wqh, Wql, Wkh, Wkl, Wvh);
  split_transpose<true ><<<dim3(512, 8, 8), tb, 0, stream>>>(edge, Xth, Xtl);
  split_transpose<false><<<dim3(512, 8, 8), tb, 0, stream>>>(mask, Mt, nullptr);

  gemm_nt<0, true><<<dim3(128, 2, 8), 256, 0, stream>>>(
      Xth, Xtl, Wqh, Wql, bq, nullptr, nullptr, nullptr, Qh, Ql, 0);
  gemm_nt<0, true><<<dim3(128, 2, 8), 256, 0, stream>>>(
      Xth, Xtl, Wkh, Wkl, bk, nullptr, nullptr, nullptr, Kh, Kl, 0);
  gemm_nt<2, false><<<dim3(128, 2, 8), 256, 0, stream>>>(
      Wvh, nullptr, Mt, nullptr, bv, nullptr, nullptr, nullptr, Vb, nullptr, 0);

  transpose_hw_bf16<<<dim3(4, 4, 2048), tb, 0, stream>>>(Vb, Vtb);

  gemm_nt<1, true><<<dim3(1024), 256, 0, stream>>>(
      Qh, Ql, Kh, Kl, nullptr, nullptr, nullptr, attW, nullptr, nullptr, 0);
  gemm_nt<1, true><<<dim3(1024), 256, 0, stream>>>(
      Qh, Ql, Kh, Kl, nullptr, nullptr, nullptr, attH, nullptr, nullptr, 1);

  softmax_kernel<<<dim3(32768), 256, 0, stream>>>(attH, attW, aHb, aWb);

  gemm_nt<3, false><<<dim3(1024, 2), 256, 0, stream>>>(
      Vtb, nullptr, aHb, nullptr, nullptr, nullptr, gamma, tmp, nullptr, nullptr, 0);
  gemm_nt<3, false><<<dim3(1024, 2), 256, 0, stream>>>(
      Vb, nullptr, aWb, nullptr, nullptr, mask, gamma, out, nullptr, nullptr, 0);

  merge_kernel<<<dim3(4, 4, 2048), tb, 0, stream>>>(tmp, out);
}

// Round 3
// 881.627 us; speedup vs baseline: 1.6292x; 1.0150x over previous
//
#include <hip/hip_runtime.h>

typedef unsigned short u16;
typedef unsigned int   u32;
typedef __attribute__((ext_vector_type(8))) short short8;
typedef __attribute__((ext_vector_type(4))) float f32x4;

#define HW_   16384
constexpr long CHW_ = 4194304L;
constexpr long NT   = 33554432L; // B*C*H*W

#define GLDS(g, l) __builtin_amdgcn_global_load_lds( \
    (const __attribute__((address_space(1))) void*)(g), \
    (__attribute__((address_space(3))) void*)(l), 16, 0, 0)

__device__ inline u16 f2bf(float x){ u32 u = __float_as_uint(x); u += 0x7fff + ((u>>16)&1); return (u16)(u>>16); }
__device__ inline float bf2f(u16 h){ return __uint_as_float(((u32)h)<<16); }

// swizzled LDS tile: 128 rows x 8 chunks of 16B (8 bf16). elem(row r, chunk c) at
// ushort index r*64 + ((c ^ (r&7))<<3). chunk c = tensor(c>>2)*4 + khi(c&3).
__device__ inline const short8* frg(const u16* T, int r, int c){
  return (const short8*)(T + r*64 + ((c ^ (r&7))<<3));
}

// MODE 0: proj q/k (split, bias by col, split-bf16 out [b][p][256])
// MODE 1: energy   (split, fp32 out att slice, dirH picks row stride)
// MODE 2: proj v   (plain, bias by row, bf16 out [b][c][p])
// MODE 3: av       (plain, gamma*acc (+mask) fp32 out rows stride HW)
template<int MODE, bool SPLIT>
__global__ __launch_bounds__(256) void gemm_nt(
    const u16* __restrict__ Ah, const u16* __restrict__ Al,
    const u16* __restrict__ Bh, const u16* __restrict__ Bl,
    const float* __restrict__ bias, const float* __restrict__ maskp,
    const float* __restrict__ gammap,
    float* __restrict__ outF, u16* __restrict__ outH, u16* __restrict__ outL,
    int dirH)
{
  constexpr int BUFU = SPLIT ? 16384 : 8192;
  __shared__ __align__(16) u16 smem[2][BUFU];

  const int t    = threadIdx.x;
  const int lane = t & 63;
  const int wid  = t >> 6;
  const int wr   = (wid >> 1) << 6;
  const int wc   = (wid & 1) << 6;

  long abase, bbase, ars, brs;
  int b = 0, m0 = 0, n0 = 0, xx = 0, s = 0, ct = 0;
  constexpr int K = (MODE == 3) ? 128 : 256;
  constexpr int NTILES = K / 32;

  if constexpr (MODE == 0) {
    b = blockIdx.z; m0 = blockIdx.x << 7; n0 = blockIdx.y << 7;
    abase = ((long)b * HW_ + m0) * 256; ars = 256;
    bbase = (long)n0 * 256;             brs = 256;
  } else if constexpr (MODE == 1) {
    s = blockIdx.x; b = s >> 7; xx = s & 127;
    abase = dirH ? ((long)b * HW_ + xx) * 256 : ((long)b * HW_ + (long)xx * 128) * 256;
    ars   = dirH ? 32768 : 256;
    bbase = abase; brs = ars;
  } else if constexpr (MODE == 2) {
    b = blockIdx.z; m0 = blockIdx.y << 7; n0 = blockIdx.x << 7;
    abase = (long)m0 * 256;             ars = 256;
    bbase = ((long)b * HW_ + n0) * 256; brs = 256;
  } else {
    s = blockIdx.x; ct = blockIdx.y; b = s >> 7; xx = s & 127;
    abase = ((long)b * 256 + (long)(ct << 7)) * HW_ + (long)xx * 128; ars = HW_;
    bbase = (long)s * HW_; brs = 128;
  }

  const u16* pA0 = Ah + abase;
  const u16* pA1 = SPLIT ? (Al + abase) : (Bh + bbase);
  const long rsA1 = SPLIT ? ars : brs;
  const u16* pB0 = SPLIT ? (Bh + bbase) : nullptr;
  const u16* pB1 = SPLIT ? (Bl + bbase) : nullptr;

  f32x4 acc[4][4];
  for (int i = 0; i < 4; i++)
    for (int j = 0; j < 4; j++)
      acc[i][j] = (f32x4){0.f, 0.f, 0.f, 0.f};

  // stage one combined tile (source-side swizzle, linear GLDS dest)
  auto stageAll = [&](int buf, int step) {
    const long ko = (long)step * 32;
    u16* T1b = &smem[buf][0];
    #pragma unroll
    for (int i = 0; i < 4; i++) {
      int r = (i << 5) + (t >> 3);
      int c = (t & 7) ^ (r & 7);
      const u16* g = (c < 4 ? pA0 + (long)r * ars : pA1 + (long)r * rsA1) + ko + ((c & 3) << 3);
      GLDS(g, T1b + (i << 11) + ((t >> 6) << 9));
    }
    if constexpr (SPLIT) {
      u16* T2b = &smem[buf][8192];
      #pragma unroll
      for (int i = 0; i < 4; i++) {
        int r = (i << 5) + (t >> 3);
        int c = (t & 7) ^ (r & 7);
        const u16* g = (c < 4 ? pB0 + (long)r * brs : pB1 + (long)r * brs) + ko + ((c & 3) << 3);
        GLDS(g, T2b + (i << 11) + ((t >> 6) << 9));
      }
    }
  };

  const int khi = lane >> 4;
  const int rl  = lane & 15;

  stageAll(0, 0);
  __syncthreads();

  for (int kt = 0; kt < NTILES; ++kt) {
    const int cur = kt & 1;
    const u16* T1 = &smem[cur][0];
    const u16* T2 = SPLIT ? &smem[cur][8192] : &smem[cur][0];

    // 1) ds_read current fragments first (so no vmcnt wait is forced before them)
    short8 ah[4], al[4], bh[4], bl[4];
    #pragma unroll
    for (int f = 0; f < 4; f++) {
      ah[f] = *frg(T1, wr + f * 16 + rl, khi);
      if constexpr (SPLIT) {
        al[f] = *frg(T1, wr + f * 16 + rl, 4 + khi);
        bh[f] = *frg(T2, wc + f * 16 + rl, khi);
        bl[f] = *frg(T2, wc + f * 16 + rl, 4 + khi);
      } else {
        bh[f] = *frg(T1, wc + f * 16 + rl, 4 + khi);
      }
    }

    // 2) issue next-tile global->LDS loads (land during MFMA phase)
    if (kt + 1 < NTILES) stageAll(cur ^ 1, kt + 1);

    // 3) MFMA cluster
    __builtin_amdgcn_s_setprio(1);
    #pragma unroll
    for (int fm = 0; fm < 4; fm++) {
      #pragma unroll
      for (int fn = 0; fn < 4; fn++) {
        acc[fm][fn] = __builtin_amdgcn_mfma_f32_16x16x32_bf16(ah[fm], bh[fn], acc[fm][fn], 0, 0, 0);
        if constexpr (SPLIT) {
          acc[fm][fn] = __builtin_amdgcn_mfma_f32_16x16x32_bf16(ah[fm], bl[fn], acc[fm][fn], 0, 0, 0);
          acc[fm][fn] = __builtin_amdgcn_mfma_f32_16x16x32_bf16(al[fm], bh[fn], acc[fm][fn], 0, 0, 0);
        }
      }
    }
    __builtin_amdgcn_s_setprio(0);

    // 4) single barrier per K-step (drains this step's prefetch, which had
    //    the whole MFMA phase to complete)
    __syncthreads();
  }

  float gma = 0.f;
  if constexpr (MODE == 3) gma = gammap[0];

  #pragma unroll
  for (int fm = 0; fm < 4; fm++) {
    #pragma unroll
    for (int fn = 0; fn < 4; fn++) {
      #pragma unroll
      for (int r = 0; r < 4; r++) {
        int lr = wr + fm * 16 + ((lane >> 4) << 2) + r;
        int lc = wc + fn * 16 + (lane & 15);
        float v = acc[fm][fn][r];
        if constexpr (MODE == 0) {
          v += bias[n0 + lc];
          long idx = ((long)b * HW_ + m0 + lr) * 256 + n0 + lc;
          u16 h = f2bf(v);
          outH[idx] = h;
          outL[idx] = f2bf(v - bf2f(h));
        } else if constexpr (MODE == 1) {
          outF[(long)s * HW_ + (long)lr * 128 + lc] = v;
        } else if constexpr (MODE == 2) {
          v += bias[m0 + lr];
          outH[((long)b * 256 + m0 + lr) * HW_ + n0 + lc] = f2bf(v);
        } else {
          long off = ((long)b * 256 + (long)(ct << 7) + lr) * HW_ + (long)xx * 128 + lc;
          float r2 = gma * v;
          if (maskp) r2 += maskp[off];
          outF[off] = r2;
        }
      }
    }
  }
}

// ---------------- fused: edge -> split bf16 [p][c], mask -> bf16 [p][c] ----------------
__global__ __launch_bounds__(256) void split_transpose2(const float* __restrict__ edge,
    const float* __restrict__ mask, u16* __restrict__ hi, u16* __restrict__ lo,
    u16* __restrict__ mt)
{
  int b = blockIdx.z, c0 = blockIdx.y << 5, p0 = blockIdx.x << 5;
  __shared__ float tileE[32][33];
  __shared__ float tileM[32][33];
  int tx = threadIdx.x, ty = threadIdx.y;
  const float* E = edge + (long)b * CHW_;
  const float* M = mask + (long)b * CHW_;
  #pragma unroll
  for (int r = 0; r < 4; r++) {
    int cc = ty + (r << 3);
    long g = (long)(c0 + cc) * HW_ + p0 + tx;
    tileE[cc][tx] = E[g];
    tileM[cc][tx] = M[g];
  }
  __syncthreads();
  #pragma unroll
  for (int r = 0; r < 4; r++) {
    int pp = ty + (r << 3);
    long idx = ((long)b * HW_ + p0 + pp) * 256 + c0 + tx;
    float x = tileE[tx][pp];
    u16 h = f2bf(x);
    hi[idx] = h;
    lo[idx] = f2bf(x - bf2f(h));
    mt[idx] = f2bf(tileM[tx][pp]);
  }
}

// ---------------- weight split ----------------
__global__ __launch_bounds__(256) void wsplit(const float* __restrict__ Wq,
    const float* __restrict__ Wk, const float* __restrict__ Wv,
    u16* qh, u16* ql, u16* kh, u16* kl, u16* vh)
{
  int i = blockIdx.x * 256 + threadIdx.x;
  float q = Wq[i]; u16 a = f2bf(q); qh[i] = a; ql[i] = f2bf(q - bf2f(a));
  float k = Wk[i]; u16 c = f2bf(k); kh[i] = c; kl[i] = f2bf(k - bf2f(c));
  vh[i] = f2bf(Wv[i]);
}

// ---------------- bf16 H<->W transpose: dst[bc][w*128+h] = src[bc][h*128+w] ----------------
__global__ __launch_bounds__(256) void transpose_hw_bf16(const u16* __restrict__ src,
                                                         u16* __restrict__ dst)
{
  int bc = blockIdx.z;
  int h0 = blockIdx.x << 5, w0 = blockIdx.y << 5;
  long base = (long)bc * HW_;
  __shared__ u16 tile[32][34];
  int tx = threadIdx.x, ty = threadIdx.y;
  #pragma unroll
  for (int r = 0; r < 4; r++)
    tile[ty + (r << 3)][tx] = src[base + (long)(h0 + ty + (r << 3)) * 128 + w0 + tx];
  __syncthreads();
  #pragma unroll
  for (int r = 0; r < 4; r++) {
    int ww = ty + (r << 3);
    dst[base + (long)(w0 + ww) * 128 + h0 + tx] = tile[tx][ww];
  }
}

// ---------------- softmax over concat(rowH[128], rowW[128]) + bf16 copies ----------------
__global__ __launch_bounds__(256) void softmax_kernel(float* __restrict__ attH,
    float* __restrict__ attW, u16* __restrict__ aHb, u16* __restrict__ aWb)
{
  int wid  = threadIdx.x >> 6;
  int lane = threadIdx.x & 63;
  long r = (long)blockIdx.x * 4 + wid;           // (b,h,w)
  int b = (int)(r >> 14);
  int h = (int)((r >> 7) & 127);
  int w = (int)(r & 127);
  long baseH = ((long)(b * 128 + w) * 128 + h) * 128;
  long baseW = r * 128;
  float* rowH = attH + baseH;
  float* rowW = attW + baseW;
  float x0 = rowH[lane], x1 = rowH[64 + lane], x2 = rowW[lane], x3 = rowW[64 + lane];
  float m = fmaxf(fmaxf(x0, x1), fmaxf(x2, x3));
  #pragma unroll
  for (int off = 32; off; off >>= 1) m = fmaxf(m, __shfl_xor(m, off, 64));
  float e0 = expf(x0 - m), e1 = expf(x1 - m), e2 = expf(x2 - m), e3 = expf(x3 - m);
  float ssum = e0 + e1 + e2 + e3;
  #pragma unroll
  for (int off = 32; off; off >>= 1) ssum += __shfl_xor(ssum, off, 64);
  float inv = 1.0f / ssum;
  float p0 = e0 * inv, p1 = e1 * inv, p2 = e2 * inv, p3 = e3 * inv;
  rowH[lane] = p0; rowH[64 + lane] = p1;
  rowW[lane] = p2; rowW[64 + lane] = p3;
  aHb[baseH + lane] = f2bf(p0); aHb[baseH + 64 + lane] = f2bf(p1);
  aWb[baseW + lane] = f2bf(p2); aWb[baseW + 64 + lane] = f2bf(p3);
}

// ---------------- merge: out[b,c,h,w] += tmp[b,c,w,h] ----------------
__global__ __launch_bounds__(256) void merge_kernel(const float* __restrict__ tmp,
                                                    float* __restrict__ out)
{
  int bc = blockIdx.z;
  int h0 = blockIdx.x << 5, w0 = blockIdx.y << 5;
  long base = (long)bc * HW_;
  __shared__ float tile[32][33];
  int tx = threadIdx.x, ty = threadIdx.y;
  #pragma unroll
  for (int r = 0; r < 4; r++) {
    int ww = ty + (r << 3);
    tile[ww][tx] = tmp[base + (long)(w0 + ww) * 128 + h0 + tx];
  }
  __syncthreads();
  #pragma unroll
  for (int r = 0; r < 4; r++) {
    int hh = ty + (r << 3);
    long o = base + (long)(h0 + hh) * 128 + w0 + tx;
    out[o] += tile[tx][hh];
  }
}

extern "C" void kernel_launch(void* const* d_in, const int* in_sizes, int n_in,
                              void* d_out, int out_size, void* d_ws, size_t ws_size,
                              hipStream_t stream) {
  const float* edge  = (const float*)d_in[0];
  const float* mask  = (const float*)d_in[1];
  const float* Wq    = (const float*)d_in[2];
  const float* bq    = (const float*)d_in[3];
  const float* Wk    = (const float*)d_in[4];
  const float* bk    = (const float*)d_in[5];
  const float* Wv    = (const float*)d_in[6];
  const float* bv    = (const float*)d_in[7];
  const float* gamma = (const float*)d_in[8];

  float* out  = (float*)d_out;
  float* attH = out + NT;            // B*W*H*H
  float* attW = attH + 16777216L;    // B*H*W*W

  char* W = (char*)d_ws;
  const long SLOT = 67108864L;       // 64 MiB
  u16* Xth = (u16*)(W + 0 * SLOT);
  u16* Xtl = (u16*)(W + 1 * SLOT);
  u16* Mt  = (u16*)(W + 2 * SLOT);
  u16* Qh  = (u16*)(W + 3 * SLOT);
  u16* Ql  = (u16*)(W + 4 * SLOT);
  u16* Kh  = (u16*)(W + 5 * SLOT);
  u16* Kl  = (u16*)(W + 6 * SLOT);
  u16* Vb  = (u16*)(W + 7 * SLOT);
  u16* Vtb = (u16*)(W + 0 * SLOT);              // reuse Xth (dead after projections)
  u16* aWb = (u16*)(W + 1 * SLOT);              // reuse Xtl (32 MiB)
  u16* aHb = (u16*)(W + 1 * SLOT + 33554432L);  // (32 MiB)
  float* tmp = (float*)(W + 3 * SLOT);          // reuse Qh/Ql (128 MiB, dead after energy)
  u16* Wqh = (u16*)(W + 8 * SLOT);
  u16* Wql = Wqh + 65536;
  u16* Wkh = Wql + 65536;
  u16* Wkl = Wkh + 65536;
  u16* Wvh = Wkl + 65536;

  dim3 tb(32, 8);

  wsplit<<<256, 256, 0, stream>>>(Wq, Wk, Wv, Wqh, Wql, Wkh, Wkl, Wvh);
  split_transpose2<<<dim3(512, 8, 8), tb, 0, stream>>>(edge, mask, Xth, Xtl, Mt);

  gemm_nt<0, true><<<dim3(128, 2, 8), 256, 0, stream>>>(
      Xth, Xtl, Wqh, Wql, bq, nullptr, nullptr, nullptr, Qh, Ql, 0);
  gemm_nt<0, true><<<dim3(128, 2, 8), 256, 0, stream>>>(
      Xth, Xtl, Wkh, Wkl, bk, nullptr, nullptr, nullptr, Kh, Kl, 0);
  gemm_nt<2, false><<<dim3(128, 2, 8), 256, 0, stream>>>(
      Wvh, nullptr, Mt, nullptr, bv, nullptr, nullptr, nullptr, Vb, nullptr, 0);

  transpose_hw_bf16<<<dim3(4, 4, 2048), tb, 0, stream>>>(Vb, Vtb);

  gemm_nt<1, true><<<dim3(1024), 256, 0, stream>>>(
      Qh, Ql, Kh, Kl, nullptr, nullptr, nullptr, attW, nullptr, nullptr, 0);
  gemm_nt<1, true><<<dim3(1024), 256, 0, stream>>>(
      Qh, Ql, Kh, Kl, nullptr, nullptr, nullptr, attH, nullptr, nullptr, 1);

  softmax_kernel<<<dim3(32768), 256, 0, stream>>>(attH, attW, aHb, aWb);

  gemm_nt<3, false><<<dim3(1024, 2), 256, 0, stream>>>(
      Vtb, nullptr, aHb, nullptr, nullptr, nullptr, gamma, tmp, nullptr, nullptr, 0);
  gemm_nt<3, false><<<dim3(1024, 2), 256, 0, stream>>>(
      Vb, nullptr, aWb, nullptr, nullptr, mask, gamma, out, nullptr, nullptr, 0);

  merge_kernel<<<dim3(4, 4, 2048), tb, 0, stream>>>(tmp, out);
}

// Round 4
// 767.818 us; speedup vs baseline: 1.8707x; 1.1482x over previous
//
#include <hip/hip_runtime.h>

typedef unsigned short u16;
typedef unsigned int   u32;
typedef __attribute__((ext_vector_type(8))) short short8;
typedef __attribute__((ext_vector_type(4))) float f32x4;

#define HW_   16384
constexpr long CHW_ = 4194304L;
constexpr long NT   = 33554432L; // B*C*H*W

#define GLDS(g, l) __builtin_amdgcn_global_load_lds( \
    (const __attribute__((address_space(1))) void*)(g), \
    (__attribute__((address_space(3))) void*)(l), 16, 0, 0)

__device__ inline u16 f2bf(float x){ u32 u = __float_as_uint(x); u += 0x7fff + ((u>>16)&1); return (u16)(u>>16); }
__device__ inline float bf2f(u16 h){ return __uint_as_float(((u32)h)<<16); }

// counted vmcnt wait; n is constant after unrolling so the if-chain folds.
__device__ inline void wait_vm(int n){
  if (n >= 16)      asm volatile("s_waitcnt vmcnt(16)" ::: "memory");
  else if (n == 12) asm volatile("s_waitcnt vmcnt(12)" ::: "memory");
  else if (n == 8)  asm volatile("s_waitcnt vmcnt(8)"  ::: "memory");
  else if (n == 4)  asm volatile("s_waitcnt vmcnt(4)"  ::: "memory");
  else              asm volatile("s_waitcnt vmcnt(0)"  ::: "memory");
}

// swizzled LDS tile: 128 rows x 8 chunks of 16B (8 bf16). elem(row r, chunk c) at
// ushort index r*64 + ((c ^ (r&7))<<3). chunk c = tensor(c>>2)*4 + khi(c&3).
__device__ inline const short8* frg(const u16* T, int r, int c){
  return (const short8*)(T + r*64 + ((c ^ (r&7))<<3));
}

// MODE 0: proj q+k fused (split A=X, B=Wcat 512 rows; split-bf16 out into Q or K bufs)
// MODE 1: energy   (split, fp32 out att slice, dirH picks row stride)
// MODE 2: proj v   (plain, bias by row, bf16 out [b][c][p])
// MODE 3: av       (plain, bf16 out gamma*acc, rows stride HW)
template<int MODE, bool SPLIT>
__global__ __launch_bounds__(256) void gemm_nt(
    const u16* __restrict__ Ah, const u16* __restrict__ Al,
    const u16* __restrict__ Bh, const u16* __restrict__ Bl,
    const float* __restrict__ bias, const float* __restrict__ gammap,
    float* __restrict__ outF, u16* __restrict__ outH, u16* __restrict__ outL,
    u16* __restrict__ outH2, u16* __restrict__ outL2, int dirH)
{
  constexpr int K    = (MODE == 3) ? 128 : 256;
  constexpr int NTl  = K / 32;                  // 4 or 8 tiles
  constexpr int BUFU = SPLIT ? 16384 : 8192;    // u16 per buffer
  constexpr int GPS  = SPLIT ? 8 : 4;           // GLDS per wave per stage
  __shared__ __align__(16) u16 smem[4][BUFU];

  const int t    = threadIdx.x;
  const int lane = t & 63;
  const int wid  = t >> 6;
  const int wr   = (wid >> 1) << 6;
  const int wc   = (wid & 1) << 6;

  long abase, bbase, ars, brs;
  int b = 0, m0 = 0, n0 = 0, xx = 0, s = 0, ct = 0;

  if constexpr (MODE == 0) {
    b = blockIdx.z; m0 = blockIdx.x << 7; n0 = blockIdx.y << 7;
    abase = ((long)b * HW_ + m0) * 256; ars = 256;
    bbase = (long)n0 * 256;             brs = 256;
  } else if constexpr (MODE == 1) {
    s = blockIdx.x; b = s >> 7; xx = s & 127;
    abase = dirH ? ((long)b * HW_ + xx) * 256 : ((long)b * HW_ + (long)xx * 128) * 256;
    ars   = dirH ? 32768 : 256;
    bbase = abase; brs = ars;
  } else if constexpr (MODE == 2) {
    b = blockIdx.z; m0 = blockIdx.y << 7; n0 = blockIdx.x << 7;
    abase = (long)m0 * 256;             ars = 256;
    bbase = ((long)b * HW_ + n0) * 256; brs = 256;
  } else {
    s = blockIdx.x; ct = blockIdx.y; b = s >> 7; xx = s & 127;
    abase = ((long)b * 256 + (long)(ct << 7)) * HW_ + (long)xx * 128; ars = HW_;
    bbase = (long)s * HW_; brs = 128;
  }

  const u16* pA0 = Ah + abase;
  const u16* pA1 = SPLIT ? (Al + abase) : (Bh + bbase);
  const long rsA1 = SPLIT ? ars : brs;
  const u16* pB0 = SPLIT ? (Bh + bbase) : nullptr;
  const u16* pB1 = SPLIT ? (Bl + bbase) : nullptr;

  f32x4 acc[4][4];
  for (int i = 0; i < 4; i++)
    for (int j = 0; j < 4; j++)
      acc[i][j] = (f32x4){0.f, 0.f, 0.f, 0.f};

  // stage one combined tile into ring buffer `buf` (source-side swizzle, linear GLDS dest)
  auto stage = [&](int buf, int step) {
    const long ko = (long)step * 32;
    u16* T1b = &smem[buf][0];
    #pragma unroll
    for (int i = 0; i < 4; i++) {
      int r = (i << 5) + (t >> 3);
      int c = (t & 7) ^ (r & 7);
      const u16* g = (c < 4 ? pA0 + (long)r * ars : pA1 + (long)r * rsA1) + ko + ((c & 3) << 3);
      GLDS(g, T1b + (i << 11) + ((t >> 6) << 9));
    }
    if constexpr (SPLIT) {
      u16* T2b = &smem[buf][8192];
      #pragma unroll
      for (int i = 0; i < 4; i++) {
        int r = (i << 5) + (t >> 3);
        int c = (t & 7) ^ (r & 7);
        const u16* g = (c < 4 ? pB0 + (long)r * brs : pB1 + (long)r * brs) + ko + ((c & 3) << 3);
        GLDS(g, T2b + (i << 11) + ((t >> 6) << 9));
      }
    }
  };

  const int khi = lane >> 4;
  const int rl  = lane & 15;

  // prologue: NTl<=4 -> stage everything (no ring reuse at all);
  // NTl==8  -> stage 0,1, then in-loop stage(t+2) into ring-4 (2-barrier reuse gap)
  if constexpr (NTl <= 4) {
    #pragma unroll
    for (int p = 0; p < NTl; ++p) stage(p, p);
  } else {
    stage(0, 0); stage(1, 1);
  }

  #pragma unroll
  for (int kt = 0; kt < NTl; ++kt) {
    if constexpr (NTl > 4) {
      if (kt + 2 < NTl) stage((kt + 2) & 3, kt + 2);
    }
    const int newer = (NTl <= 4) ? (NTl - 1 - kt)
                                 : ((kt + 2 < NTl ? kt + 2 : NTl - 1) - kt);
    wait_vm(newer * GPS);
    __builtin_amdgcn_sched_barrier(0);
    __builtin_amdgcn_s_barrier();
    __builtin_amdgcn_sched_barrier(0);

    const u16* T1 = &smem[kt & 3][0];
    const u16* T2 = SPLIT ? &smem[kt & 3][8192] : &smem[kt & 3][0];

    short8 ah[4], al[4], bh[4], bl[4];
    #pragma unroll
    for (int f = 0; f < 4; f++) {
      ah[f] = *frg(T1, wr + f * 16 + rl, khi);
      if constexpr (SPLIT) {
        al[f] = *frg(T1, wr + f * 16 + rl, 4 + khi);
        bh[f] = *frg(T2, wc + f * 16 + rl, khi);
        bl[f] = *frg(T2, wc + f * 16 + rl, 4 + khi);
      } else {
        bh[f] = *frg(T1, wc + f * 16 + rl, 4 + khi);
      }
    }

    __builtin_amdgcn_s_setprio(1);
    #pragma unroll
    for (int fm = 0; fm < 4; fm++) {
      #pragma unroll
      for (int fn = 0; fn < 4; fn++) {
        acc[fm][fn] = __builtin_amdgcn_mfma_f32_16x16x32_bf16(ah[fm], bh[fn], acc[fm][fn], 0, 0, 0);
        if constexpr (SPLIT) {
          acc[fm][fn] = __builtin_amdgcn_mfma_f32_16x16x32_bf16(ah[fm], bl[fn], acc[fm][fn], 0, 0, 0);
          acc[fm][fn] = __builtin_amdgcn_mfma_f32_16x16x32_bf16(al[fm], bh[fn], acc[fm][fn], 0, 0, 0);
        }
      }
    }
    __builtin_amdgcn_s_setprio(0);
  }

  float gma = 0.f;
  if constexpr (MODE == 3) gma = gammap[0];

  #pragma unroll
  for (int fm = 0; fm < 4; fm++) {
    #pragma unroll
    for (int fn = 0; fn < 4; fn++) {
      #pragma unroll
      for (int r = 0; r < 4; r++) {
        int lr = wr + fm * 16 + ((lane >> 4) << 2) + r;
        int lc = wc + fn * 16 + (lane & 15);
        float v = acc[fm][fn][r];
        if constexpr (MODE == 0) {
          float v2 = v + bias[n0 + lc];
          int col = (n0 + lc) & 255;
          long idx = ((long)b * HW_ + m0 + lr) * 256 + col;
          u16 h = f2bf(v2);
          u16 l = f2bf(v2 - bf2f(h));
          if (n0 < 256) { outH[idx] = h; outL[idx] = l; }
          else          { outH2[idx] = h; outL2[idx] = l; }
        } else if constexpr (MODE == 1) {
          outF[(long)s * HW_ + (long)lr * 128 + lc] = v;
        } else if constexpr (MODE == 2) {
          v += bias[m0 + lr];
          outH[((long)b * 256 + m0 + lr) * HW_ + n0 + lc] = f2bf(v);
        } else {
          long off = ((long)b * 256 + (long)(ct << 7) + lr) * HW_ + (long)xx * 128 + lc;
          outH[off] = f2bf(gma * v);
        }
      }
    }
  }
}

// ---------------- fused: edge -> split bf16 [p][c], mask -> bf16 [p][c] ----------------
__global__ __launch_bounds__(256) void split_transpose2(const float* __restrict__ edge,
    const float* __restrict__ mask, u16* __restrict__ hi, u16* __restrict__ lo,
    u16* __restrict__ mt)
{
  int b = blockIdx.z, c0 = blockIdx.y << 5, p0 = blockIdx.x << 5;
  __shared__ float tileE[32][33];
  __shared__ float tileM[32][33];
  int tx = threadIdx.x, ty = threadIdx.y;
  const float* E = edge + (long)b * CHW_;
  const float* M = mask + (long)b * CHW_;
  #pragma unroll
  for (int r = 0; r < 4; r++) {
    int cc = ty + (r << 3);
    long g = (long)(c0 + cc) * HW_ + p0 + tx;
    tileE[cc][tx] = E[g];
    tileM[cc][tx] = M[g];
  }
  __syncthreads();
  #pragma unroll
  for (int r = 0; r < 4; r++) {
    int pp = ty + (r << 3);
    long idx = ((long)b * HW_ + p0 + pp) * 256 + c0 + tx;
    float x = tileE[tx][pp];
    u16 h = f2bf(x);
    hi[idx] = h;
    lo[idx] = f2bf(x - bf2f(h));
    mt[idx] = f2bf(tileM[tx][pp]);
  }
}

// ---------------- weight prep: Wcat = [Wq;Wk] split hi/lo, Wv plain, bias cat ----------------
__global__ __launch_bounds__(256) void wsplit(const float* __restrict__ Wq,
    const float* __restrict__ Wk, const float* __restrict__ Wv,
    const float* __restrict__ bq, const float* __restrict__ bk,
    u16* cath, u16* catl, u16* vh, float* bcat)
{
  int i = blockIdx.x * 256 + threadIdx.x;
  float q = Wq[i]; u16 a = f2bf(q); cath[i] = a; catl[i] = f2bf(q - bf2f(a));
  float k = Wk[i]; u16 c = f2bf(k); cath[65536 + i] = c; catl[65536 + i] = f2bf(k - bf2f(c));
  vh[i] = f2bf(Wv[i]);
  if (blockIdx.x == 0) {
    bcat[threadIdx.x]       = bq[threadIdx.x];
    bcat[256 + threadIdx.x] = bk[threadIdx.x];
  }
}

// ---------------- bf16 H<->W transpose: dst[bc][w*128+h] = src[bc][h*128+w] ----------------
__global__ __launch_bounds__(256) void transpose_hw_bf16(const u16* __restrict__ src,
                                                         u16* __restrict__ dst)
{
  int bc = blockIdx.z;
  int h0 = blockIdx.x << 5, w0 = blockIdx.y << 5;
  long base = (long)bc * HW_;
  __shared__ u16 tile[32][34];
  int tx = threadIdx.x, ty = threadIdx.y;
  #pragma unroll
  for (int r = 0; r < 4; r++)
    tile[ty + (r << 3)][tx] = src[base + (long)(h0 + ty + (r << 3)) * 128 + w0 + tx];
  __syncthreads();
  #pragma unroll
  for (int r = 0; r < 4; r++) {
    int ww = ty + (r << 3);
    dst[base + (long)(w0 + ww) * 128 + h0 + tx] = tile[tx][ww];
  }
}

// ---------------- softmax over concat(rowH[128], rowW[128]) + bf16 copies ----------------
__global__ __launch_bounds__(256) void softmax_kernel(float* __restrict__ attH,
    float* __restrict__ attW, u16* __restrict__ aHb, u16* __restrict__ aWb)
{
  int wid  = threadIdx.x >> 6;
  int lane = threadIdx.x & 63;
  long r = (long)blockIdx.x * 4 + wid;           // (b,h,w)
  int b = (int)(r >> 14);
  int h = (int)((r >> 7) & 127);
  int w = (int)(r & 127);
  long baseH = ((long)(b * 128 + w) * 128 + h) * 128;
  long baseW = r * 128;
  float* rowH = attH + baseH;
  float* rowW = attW + baseW;
  float x0 = rowH[lane], x1 = rowH[64 + lane], x2 = rowW[lane], x3 = rowW[64 + lane];
  float m = fmaxf(fmaxf(x0, x1), fmaxf(x2, x3));
  #pragma unroll
  for (int off = 32; off; off >>= 1) m = fmaxf(m, __shfl_xor(m, off, 64));
  float e0 = expf(x0 - m), e1 = expf(x1 - m), e2 = expf(x2 - m), e3 = expf(x3 - m);
  float ssum = e0 + e1 + e2 + e3;
  #pragma unroll
  for (int off = 32; off; off >>= 1) ssum += __shfl_xor(ssum, off, 64);
  float inv = 1.0f / ssum;
  float p0 = e0 * inv, p1 = e1 * inv, p2 = e2 * inv, p3 = e3 * inv;
  rowH[lane] = p0; rowH[64 + lane] = p1;
  rowW[lane] = p2; rowW[64 + lane] = p3;
  aHb[baseH + lane] = f2bf(p0); aHb[baseH + 64 + lane] = f2bf(p1);
  aWb[baseW + lane] = f2bf(p2); aWb[baseW + 64 + lane] = f2bf(p3);
}

// ---------------- merge: out[b,c,h,w] = pW[b,c,h,w] + tmp[b,c,w,h] + mask[b,c,h,w] -------
__global__ __launch_bounds__(256) void merge_kernel(const u16* __restrict__ tmp,
    const u16* __restrict__ pW, const float* __restrict__ mask, float* __restrict__ out)
{
  int bc = blockIdx.z;
  int h0 = blockIdx.x << 5, w0 = blockIdx.y << 5;
  long base = (long)bc * HW_;
  __shared__ u16 tile[32][33];
  int tx = threadIdx.x, ty = threadIdx.y;
  #pragma unroll
  for (int r = 0; r < 4; r++) {
    int ww = ty + (r << 3);
    tile[ww][tx] = tmp[base + (long)(w0 + ww) * 128 + h0 + tx];
  }
  __syncthreads();
  #pragma unroll
  for (int r = 0; r < 4; r++) {
    int hh = ty + (r << 3);
    long o = base + (long)(h0 + hh) * 128 + w0 + tx;
    out[o] = bf2f(pW[o]) + bf2f(tile[tx][hh]) + mask[o];
  }
}

extern "C" void kernel_launch(void* const* d_in, const int* in_sizes, int n_in,
                              void* d_out, int out_size, void* d_ws, size_t ws_size,
                              hipStream_t stream) {
  const float* edge  = (const float*)d_in[0];
  const float* mask  = (const float*)d_in[1];
  const float* Wq    = (const float*)d_in[2];
  const float* bq    = (const float*)d_in[3];
  const float* Wk    = (const float*)d_in[4];
  const float* bk    = (const float*)d_in[5];
  const float* Wv    = (const float*)d_in[6];
  const float* bv    = (const float*)d_in[7];
  const float* gamma = (const float*)d_in[8];

  float* out  = (float*)d_out;
  float* attH = out + NT;            // B*W*H*H
  float* attW = attH + 16777216L;    // B*H*W*W

  char* W = (char*)d_ws;
  const long SLOT = 67108864L;       // 64 MiB
  u16* Xth = (u16*)(W + 0 * SLOT);
  u16* Xtl = (u16*)(W + 1 * SLOT);
  u16* Mt  = (u16*)(W + 2 * SLOT);
  u16* Qh  = (u16*)(W + 3 * SLOT);
  u16* Ql  = (u16*)(W + 4 * SLOT);
  u16* Kh  = (u16*)(W + 5 * SLOT);
  u16* Kl  = (u16*)(W + 6 * SLOT);
  u16* Vb  = (u16*)(W + 7 * SLOT);
  u16* Vtb = (u16*)(W + 0 * SLOT);              // reuse Xth (dead after proj)
  u16* aWb = (u16*)(W + 1 * SLOT);              // reuse Xtl (32 MiB)
  u16* aHb = (u16*)(W + 1 * SLOT + 33554432L);  // (32 MiB)
  u16* tmp = (u16*)(W + 3 * SLOT);              // reuse Qh (dead after energy), 64 MiB
  u16* pW  = (u16*)(W + 4 * SLOT);              // reuse Ql, 64 MiB
  u16* Wch = (u16*)(W + 8 * SLOT);              // 512x256 hi
  u16* Wcl = Wch + 131072;                      // 512x256 lo
  u16* Wvh = Wcl + 131072;                      // 256x256
  float* bcat = (float*)(Wvh + 65536);          // 512 floats

  dim3 tb(32, 8);

  wsplit<<<256, 256, 0, stream>>>(Wq, Wk, Wv, bq, bk, Wch, Wcl, Wvh, bcat);
  split_transpose2<<<dim3(512, 8, 8), tb, 0, stream>>>(edge, mask, Xth, Xtl, Mt);

  // fused q+k projection: reads X-split once, writes Q and K split buffers
  gemm_nt<0, true><<<dim3(128, 4, 8), 256, 0, stream>>>(
      Xth, Xtl, Wch, Wcl, bcat, nullptr, nullptr, Qh, Ql, Kh, Kl, 0);
  // v projection
  gemm_nt<2, false><<<dim3(128, 2, 8), 256, 0, stream>>>(
      Wvh, nullptr, Mt, nullptr, bv, nullptr, nullptr, Vb, nullptr, nullptr, nullptr, 0);

  transpose_hw_bf16<<<dim3(4, 4, 2048), tb, 0, stream>>>(Vb, Vtb);

  gemm_nt<1, true><<<dim3(1024), 256, 0, stream>>>(
      Qh, Ql, Kh, Kl, nullptr, nullptr, attW, nullptr, nullptr, nullptr, nullptr, 0);
  gemm_nt<1, true><<<dim3(1024), 256, 0, stream>>>(
      Qh, Ql, Kh, Kl, nullptr, nullptr, attH, nullptr, nullptr, nullptr, nullptr, 1);

  softmax_kernel<<<dim3(32768), 256, 0, stream>>>(attH, attW, aHb, aWb);

  // av H-direction -> bf16 tmp[b,c,w,h]; av W-direction -> bf16 pW[b,c,h,w]
  gemm_nt<3, false><<<dim3(1024, 2), 256, 0, stream>>>(
      Vtb, nullptr, aHb, nullptr, nullptr, gamma, nullptr, tmp, nullptr, nullptr, nullptr, 0);
  gemm_nt<3, false><<<dim3(1024, 2), 256, 0, stream>>>(
      Vb, nullptr, aWb, nullptr, nullptr, gamma, nullptr, pW, nullptr, nullptr, nullptr, 0);

  merge_kernel<<<dim3(4, 4, 2048), tb, 0, stream>>>(tmp, pW, mask, out);
}

// Round 5
// 745.864 us; speedup vs baseline: 1.9258x; 1.0294x over previous
//
#include <hip/hip_runtime.h>

typedef unsigned short u16;
typedef unsigned int   u32;
typedef __attribute__((ext_vector_type(8))) short short8;
typedef __attribute__((ext_vector_type(4))) float f32x4;

#define HW_   16384
constexpr long CHW_ = 4194304L;
constexpr long NT   = 33554432L; // B*C*H*W

#define GLDS(g, l) __builtin_amdgcn_global_load_lds( \
    (const __attribute__((address_space(1))) void*)(g), \
    (__attribute__((address_space(3))) void*)(l), 16, 0, 0)

__device__ inline u16 f2bf(float x){ u32 u = __float_as_uint(x); u += 0x7fff + ((u>>16)&1); return (u16)(u>>16); }
__device__ inline float bf2f(u16 h){ return __uint_as_float(((u32)h)<<16); }

// counted vmcnt wait; n is constant after unrolling so the if-chain folds.
__device__ inline void wait_vm(int n){
  if (n >= 8)       asm volatile("s_waitcnt vmcnt(8)"  ::: "memory");
  else if (n == 4)  asm volatile("s_waitcnt vmcnt(4)"  ::: "memory");
  else              asm volatile("s_waitcnt vmcnt(0)"  ::: "memory");
}

// swizzled LDS tile: 128 rows x 8 chunks of 16B (8 bf16). elem(row r, chunk c) at
// ushort index r*64 + ((c ^ (r&7))<<3). chunk c = tensor(c>>2)*4 + khi(c&3).
__device__ inline const short8* frg(const u16* T, int r, int c){
  return (const short8*)(T + r*64 + ((c ^ (r&7))<<3));
}

// MODE 0: proj q+k fused (split A=X, B=Wcat 512 rows; split-bf16 out into Q or K bufs)
// MODE 1: energy   (split, fp32 out att slice, dirH picks row stride)
// MODE 2: proj v   (plain, bias by row, bf16 out [b][c][p])
// MODE 3: av       (plain, bf16 out gamma*acc, rows stride HW)
template<int MODE, bool SPLIT>
__global__ __launch_bounds__(256) void gemm_nt(
    const u16* __restrict__ Ah, const u16* __restrict__ Al,
    const u16* __restrict__ Bh, const u16* __restrict__ Bl,
    const float* __restrict__ bias, const float* __restrict__ gammap,
    float* __restrict__ outF, u16* __restrict__ outH, u16* __restrict__ outL,
    u16* __restrict__ outH2, u16* __restrict__ outL2, int dirH)
{
  constexpr int K    = (MODE == 3) ? 128 : 256;
  constexpr int NTl  = K / 32;                  // 4 or 8 K-tiles
  constexpr int BUFU = SPLIT ? 16384 : 8192;    // u16 per ring buffer
  constexpr int GPS  = SPLIT ? 8 : 4;           // GLDS per thread per stage
  __shared__ __align__(16) u16 smem[2][BUFU];   // ring-2: 64 KB split / 32 KB plain

  const int t    = threadIdx.x;
  const int lane = t & 63;
  const int wid  = t >> 6;
  const int wr   = (wid >> 1) << 6;
  const int wc   = (wid & 1) << 6;

  long abase, bbase, ars, brs;
  int b = 0, m0 = 0, n0 = 0, xx = 0, s = 0, ct = 0;

  if constexpr (MODE == 0) {
    b = blockIdx.z; m0 = blockIdx.x << 7; n0 = blockIdx.y << 7;
    abase = ((long)b * HW_ + m0) * 256; ars = 256;
    bbase = (long)n0 * 256;             brs = 256;
  } else if constexpr (MODE == 1) {
    s = blockIdx.x; b = s >> 7; xx = s & 127;
    abase = dirH ? ((long)b * HW_ + xx) * 256 : ((long)b * HW_ + (long)xx * 128) * 256;
    ars   = dirH ? 32768 : 256;
    bbase = abase; brs = ars;
  } else if constexpr (MODE == 2) {
    b = blockIdx.z; m0 = blockIdx.y << 7; n0 = blockIdx.x << 7;
    abase = (long)m0 * 256;             ars = 256;
    bbase = ((long)b * HW_ + n0) * 256; brs = 256;
  } else {
    s = blockIdx.x; ct = blockIdx.y; b = s >> 7; xx = s & 127;
    abase = ((long)b * 256 + (long)(ct << 7)) * HW_ + (long)xx * 128; ars = HW_;
    bbase = (long)s * HW_; brs = 128;
  }

  const u16* pA0 = Ah + abase;
  const u16* pA1 = SPLIT ? (Al + abase) : (Bh + bbase);
  const long rsA1 = SPLIT ? ars : brs;
  const u16* pB0 = SPLIT ? (Bh + bbase) : nullptr;
  const u16* pB1 = SPLIT ? (Bl + bbase) : nullptr;

  f32x4 acc[4][4];
  for (int i = 0; i < 4; i++)
    for (int j = 0; j < 4; j++)
      acc[i][j] = (f32x4){0.f, 0.f, 0.f, 0.f};

  // stage one combined tile into ring buffer `buf` (source-side swizzle, linear GLDS dest)
  auto stage = [&](int buf, int step) {
    const long ko = (long)step * 32;
    u16* T1b = &smem[buf][0];
    #pragma unroll
    for (int i = 0; i < 4; i++) {
      int r = (i << 5) + (t >> 3);
      int c = (t & 7) ^ (r & 7);
      const u16* g = (c < 4 ? pA0 + (long)r * ars : pA1 + (long)r * rsA1) + ko + ((c & 3) << 3);
      GLDS(g, T1b + (i << 11) + ((t >> 6) << 9));
    }
    if constexpr (SPLIT) {
      u16* T2b = &smem[buf][8192];
      #pragma unroll
      for (int i = 0; i < 4; i++) {
        int r = (i << 5) + (t >> 3);
        int c = (t & 7) ^ (r & 7);
        const u16* g = (c < 4 ? pB0 + (long)r * brs : pB1 + (long)r * brs) + ko + ((c & 3) << 3);
        GLDS(g, T2b + (i << 11) + ((t >> 6) << 9));
      }
    }
  };

  const int khi = lane >> 4;
  const int rl  = lane & 15;

  stage(0, 0);
  stage(1, 1);

  #pragma unroll
  for (int kt = 0; kt < NTl; ++kt) {
    // stage kt must have landed; stage kt+1 may still be in flight (never drain to 0 mid-loop)
    wait_vm((kt + 1 < NTl ? 1 : 0) * GPS);
    __builtin_amdgcn_sched_barrier(0);
    __builtin_amdgcn_s_barrier();
    __builtin_amdgcn_sched_barrier(0);

    const u16* T1 = &smem[kt & 1][0];
    const u16* T2 = SPLIT ? &smem[kt & 1][8192] : &smem[kt & 1][0];

    short8 ah[4], al[4], bh[4], bl[4];
    #pragma unroll
    for (int f = 0; f < 4; f++) {
      ah[f] = *frg(T1, wr + f * 16 + rl, khi);
      if constexpr (SPLIT) {
        al[f] = *frg(T1, wr + f * 16 + rl, 4 + khi);
        bh[f] = *frg(T2, wc + f * 16 + rl, khi);
        bl[f] = *frg(T2, wc + f * 16 + rl, 4 + khi);
      } else {
        bh[f] = *frg(T1, wc + f * 16 + rl, 4 + khi);
      }
    }

    __builtin_amdgcn_s_setprio(1);
    #pragma unroll
    for (int fm = 0; fm < 4; fm++) {
      #pragma unroll
      for (int fn = 0; fn < 4; fn++) {
        acc[fm][fn] = __builtin_amdgcn_mfma_f32_16x16x32_bf16(ah[fm], bh[fn], acc[fm][fn], 0, 0, 0);
        if constexpr (SPLIT) {
          acc[fm][fn] = __builtin_amdgcn_mfma_f32_16x16x32_bf16(ah[fm], bl[fn], acc[fm][fn], 0, 0, 0);
          acc[fm][fn] = __builtin_amdgcn_mfma_f32_16x16x32_bf16(al[fm], bh[fn], acc[fm][fn], 0, 0, 0);
        }
      }
    }
    __builtin_amdgcn_s_setprio(0);

    // compute-done barrier: all waves finished ds_reads of buf kt&1 (their lgkmcnt
    // drained before their MFMAs), so it is safe to overwrite it with stage kt+2.
    __builtin_amdgcn_s_barrier();
    __builtin_amdgcn_sched_barrier(0);
    if (kt + 2 < NTl) stage(kt & 1, kt + 2);
  }

  float gma = 0.f;
  if constexpr (MODE == 3) gma = gammap[0];

  #pragma unroll
  for (int fm = 0; fm < 4; fm++) {
    #pragma unroll
    for (int fn = 0; fn < 4; fn++) {
      #pragma unroll
      for (int r = 0; r < 4; r++) {
        int lr = wr + fm * 16 + ((lane >> 4) << 2) + r;
        int lc = wc + fn * 16 + (lane & 15);
        float v = acc[fm][fn][r];
        if constexpr (MODE == 0) {
          float v2 = v + bias[n0 + lc];
          int col = (n0 + lc) & 255;
          long idx = ((long)b * HW_ + m0 + lr) * 256 + col;
          u16 h = f2bf(v2);
          u16 l = f2bf(v2 - bf2f(h));
          if (n0 < 256) { outH[idx] = h; outL[idx] = l; }
          else          { outH2[idx] = h; outL2[idx] = l; }
        } else if constexpr (MODE == 1) {
          outF[(long)s * HW_ + (long)lr * 128 + lc] = v;
        } else if constexpr (MODE == 2) {
          v += bias[m0 + lr];
          outH[((long)b * 256 + m0 + lr) * HW_ + n0 + lc] = f2bf(v);
        } else {
          long off = ((long)b * 256 + (long)(ct << 7) + lr) * HW_ + (long)xx * 128 + lc;
          outH[off] = f2bf(gma * v);
        }
      }
    }
  }
}

// ---------------- fused: edge -> split bf16 [p][c], mask -> bf16 [p][c] ----------------
__global__ __launch_bounds__(256) void split_transpose2(const float* __restrict__ edge,
    const float* __restrict__ mask, u16* __restrict__ hi, u16* __restrict__ lo,
    u16* __restrict__ mt)
{
  int b = blockIdx.z, c0 = blockIdx.y << 5, p0 = blockIdx.x << 5;
  __shared__ float tileE[32][33];
  __shared__ float tileM[32][33];
  int tx = threadIdx.x, ty = threadIdx.y;
  const float* E = edge + (long)b * CHW_;
  const float* M = mask + (long)b * CHW_;
  #pragma unroll
  for (int r = 0; r < 4; r++) {
    int cc = ty + (r << 3);
    long g = (long)(c0 + cc) * HW_ + p0 + tx;
    tileE[cc][tx] = E[g];
    tileM[cc][tx] = M[g];
  }
  __syncthreads();
  #pragma unroll
  for (int r = 0; r < 4; r++) {
    int pp = ty + (r << 3);
    long idx = ((long)b * HW_ + p0 + pp) * 256 + c0 + tx;
    float x = tileE[tx][pp];
    u16 h = f2bf(x);
    hi[idx] = h;
    lo[idx] = f2bf(x - bf2f(h));
    mt[idx] = f2bf(tileM[tx][pp]);
  }
}

// ---------------- weight prep: Wcat = [Wq;Wk] split hi/lo, Wv plain, bias cat ----------------
__global__ __launch_bounds__(256) void wsplit(const float* __restrict__ Wq,
    const float* __restrict__ Wk, const float* __restrict__ Wv,
    const float* __restrict__ bq, const float* __restrict__ bk,
    u16* cath, u16* catl, u16* vh, float* bcat)
{
  int i = blockIdx.x * 256 + threadIdx.x;
  float q = Wq[i]; u16 a = f2bf(q); cath[i] = a; catl[i] = f2bf(q - bf2f(a));
  float k = Wk[i]; u16 c = f2bf(k); cath[65536 + i] = c; catl[65536 + i] = f2bf(k - bf2f(c));
  vh[i] = f2bf(Wv[i]);
  if (blockIdx.x == 0) {
    bcat[threadIdx.x]       = bq[threadIdx.x];
    bcat[256 + threadIdx.x] = bk[threadIdx.x];
  }
}

// ---------------- bf16 H<->W transpose: dst[bc][w*128+h] = src[bc][h*128+w] ----------------
__global__ __launch_bounds__(256) void transpose_hw_bf16(const u16* __restrict__ src,
                                                         u16* __restrict__ dst)
{
  int bc = blockIdx.z;
  int h0 = blockIdx.x << 5, w0 = blockIdx.y << 5;
  long base = (long)bc * HW_;
  __shared__ u16 tile[32][34];
  int tx = threadIdx.x, ty = threadIdx.y;
  #pragma unroll
  for (int r = 0; r < 4; r++)
    tile[ty + (r << 3)][tx] = src[base + (long)(h0 + ty + (r << 3)) * 128 + w0 + tx];
  __syncthreads();
  #pragma unroll
  for (int r = 0; r < 4; r++) {
    int ww = ty + (r << 3);
    dst[base + (long)(w0 + ww) * 128 + h0 + tx] = tile[tx][ww];
  }
}

// ---------------- softmax over concat(rowH[128], rowW[128]) + bf16 copies ----------------
__global__ __launch_bounds__(256) void softmax_kernel(float* __restrict__ attH,
    float* __restrict__ attW, u16* __restrict__ aHb, u16* __restrict__ aWb)
{
  int wid  = threadIdx.x >> 6;
  int lane = threadIdx.x & 63;
  long r = (long)blockIdx.x * 4 + wid;           // (b,h,w)
  int b = (int)(r >> 14);
  int h = (int)((r >> 7) & 127);
  int w = (int)(r & 127);
  long baseH = ((long)(b * 128 + w) * 128 + h) * 128;
  long baseW = r * 128;
  float* rowH = attH + baseH;
  float* rowW = attW + baseW;
  float x0 = rowH[lane], x1 = rowH[64 + lane], x2 = rowW[lane], x3 = rowW[64 + lane];
  float m = fmaxf(fmaxf(x0, x1), fmaxf(x2, x3));
  #pragma unroll
  for (int off = 32; off; off >>= 1) m = fmaxf(m, __shfl_xor(m, off, 64));
  float e0 = expf(x0 - m), e1 = expf(x1 - m), e2 = expf(x2 - m), e3 = expf(x3 - m);
  float ssum = e0 + e1 + e2 + e3;
  #pragma unroll
  for (int off = 32; off; off >>= 1) ssum += __shfl_xor(ssum, off, 64);
  float inv = 1.0f / ssum;
  float p0 = e0 * inv, p1 = e1 * inv, p2 = e2 * inv, p3 = e3 * inv;
  rowH[lane] = p0; rowH[64 + lane] = p1;
  rowW[lane] = p2; rowW[64 + lane] = p3;
  aHb[baseH + lane] = f2bf(p0); aHb[baseH + 64 + lane] = f2bf(p1);
  aWb[baseW + lane] = f2bf(p2); aWb[baseW + 64 + lane] = f2bf(p3);
}

// ---------------- merge: out[b,c,h,w] = pW[b,c,h,w] + tmp[b,c,w,h] + mask[b,c,h,w] -------
__global__ __launch_bounds__(256) void merge_kernel(const u16* __restrict__ tmp,
    const u16* __restrict__ pW, const float* __restrict__ mask, float* __restrict__ out)
{
  int bc = blockIdx.z;
  int h0 = blockIdx.x << 5, w0 = blockIdx.y << 5;
  long base = (long)bc * HW_;
  __shared__ u16 tile[32][33];
  int tx = threadIdx.x, ty = threadIdx.y;
  #pragma unroll
  for (int r = 0; r < 4; r++) {
    int ww = ty + (r << 3);
    tile[ww][tx] = tmp[base + (long)(w0 + ww) * 128 + h0 + tx];
  }
  __syncthreads();
  #pragma unroll
  for (int r = 0; r < 4; r++) {
    int hh = ty + (r << 3);
    long o = base + (long)(h0 + hh) * 128 + w0 + tx;
    out[o] = bf2f(pW[o]) + bf2f(tile[tx][hh]) + mask[o];
  }
}

extern "C" void kernel_launch(void* const* d_in, const int* in_sizes, int n_in,
                              void* d_out, int out_size, void* d_ws, size_t ws_size,
                              hipStream_t stream) {
  const float* edge  = (const float*)d_in[0];
  const float* mask  = (const float*)d_in[1];
  const float* Wq    = (const float*)d_in[2];
  const float* bq    = (const float*)d_in[3];
  const float* Wk    = (const float*)d_in[4];
  const float* bk    = (const float*)d_in[5];
  const float* Wv    = (const float*)d_in[6];
  const float* bv    = (const float*)d_in[7];
  const float* gamma = (const float*)d_in[8];

  float* out  = (float*)d_out;
  float* attH = out + NT;            // B*W*H*H
  float* attW = attH + 16777216L;    // B*H*W*W

  char* W = (char*)d_ws;
  const long SLOT = 67108864L;       // 64 MiB
  u16* Xth = (u16*)(W + 0 * SLOT);
  u16* Xtl = (u16*)(W + 1 * SLOT);
  u16* Mt  = (u16*)(W + 2 * SLOT);
  u16* Qh  = (u16*)(W + 3 * SLOT);
  u16* Ql  = (u16*)(W + 4 * SLOT);
  u16* Kh  = (u16*)(W + 5 * SLOT);
  u16* Kl  = (u16*)(W + 6 * SLOT);
  u16* Vb  = (u16*)(W + 7 * SLOT);
  u16* Vtb = (u16*)(W + 0 * SLOT);              // reuse Xth (dead after proj)
  u16* aWb = (u16*)(W + 1 * SLOT);              // reuse Xtl (32 MiB)
  u16* aHb = (u16*)(W + 1 * SLOT + 33554432L);  // (32 MiB)
  u16* tmp = (u16*)(W + 3 * SLOT);              // reuse Qh (dead after energy), 64 MiB
  u16* pW  = (u16*)(W + 4 * SLOT);              // reuse Ql, 64 MiB
  u16* Wch = (u16*)(W + 8 * SLOT);              // 512x256 hi
  u16* Wcl = Wch + 131072;                      // 512x256 lo
  u16* Wvh = Wcl + 131072;                      // 256x256
  float* bcat = (float*)(Wvh + 65536);          // 512 floats

  dim3 tb(32, 8);

  wsplit<<<256, 256, 0, stream>>>(Wq, Wk, Wv, bq, bk, Wch, Wcl, Wvh, bcat);
  split_transpose2<<<dim3(512, 8, 8), tb, 0, stream>>>(edge, mask, Xth, Xtl, Mt);

  // fused q+k projection: reads X-split once, writes Q and K split buffers
  gemm_nt<0, true><<<dim3(128, 4, 8), 256, 0, stream>>>(
      Xth, Xtl, Wch, Wcl, bcat, nullptr, nullptr, Qh, Ql, Kh, Kl, 0);
  // v projection
  gemm_nt<2, false><<<dim3(128, 2, 8), 256, 0, stream>>>(
      Wvh, nullptr, Mt, nullptr, bv, nullptr, nullptr, Vb, nullptr, nullptr, nullptr, 0);

  transpose_hw_bf16<<<dim3(4, 4, 2048), tb, 0, stream>>>(Vb, Vtb);

  gemm_nt<1, true><<<dim3(1024), 256, 0, stream>>>(
      Qh, Ql, Kh, Kl, nullptr, nullptr, attW, nullptr, nullptr, nullptr, nullptr, 0);
  gemm_nt<1, true><<<dim3(1024), 256, 0, stream>>>(
      Qh, Ql, Kh, Kl, nullptr, nullptr, attH, nullptr, nullptr, nullptr, nullptr, 1);

  softmax_kernel<<<dim3(32768), 256, 0, stream>>>(attH, attW, aHb, aWb);

  // av H-direction -> bf16 tmp[b,c,w,h]; av W-direction -> bf16 pW[b,c,h,w]
  gemm_nt<3, false><<<dim3(1024, 2), 256, 0, stream>>>(
      Vtb, nullptr, aHb, nullptr, nullptr, gamma, nullptr, tmp, nullptr, nullptr, nullptr, 0);
  gemm_nt<3, false><<<dim3(1024, 2), 256, 0, stream>>>(
      Vb, nullptr, aWb, nullptr, nullptr, gamma, nullptr, pW, nullptr, nullptr, nullptr, 0);

  merge_kernel<<<dim3(4, 4, 2048), tb, 0, stream>>>(tmp, pW, mask, out);
}

// Round 6
// 634.316 us; speedup vs baseline: 2.2644x; 1.1759x over previous
//
#include <hip/hip_runtime.h>

typedef unsigned short u16;
typedef unsigned int   u32;
typedef __attribute__((ext_vector_type(8))) short short8;
typedef __attribute__((ext_vector_type(4))) float f32x4;

#define HW_   16384
constexpr long CHW_ = 4194304L;
constexpr long NT   = 33554432L; // B*C*H*W

#define GLDS(g, l) __builtin_amdgcn_global_load_lds( \
    (const __attribute__((address_space(1))) void*)(g), \
    (__attribute__((address_space(3))) void*)(l), 16, 0, 0)

__device__ inline u16 f2bf(float x){ u32 u = __float_as_uint(x); u += 0x7fff + ((u>>16)&1); return (u16)(u>>16); }
__device__ inline float bf2f(u16 h){ return __uint_as_float(((u32)h)<<16); }

// swizzled LDS tile: 128 rows x 8 chunks of 16B. elem(row r, chunk c) at
// u16 index r*64 + ((c ^ (r&7))<<3).
__device__ inline const short8* frg(const u16* T, int r, int c){
  return (const short8*)(T + r*64 + ((c ^ (r&7))<<3));
}

// Split layout (X/Q/K/Wcat): row = 512 u16 = 8 blocks of [32 hi | 32 lo] (1024 B).
// Plain layout (Mt/V/att/Wv): row = K-contiguous bf16.
// Every K-step stages 128 B per row per tensor (8 chunks of 16 B, source-swizzled).

// MODE 0: proj q+k fused (split A=Xs, B=Wcat 512 rows; interleaved split out -> Qs/Ks)
// MODE 1: energy both dirs (split A=Qs,B=Ks; fp32 out att slice; dir from blockIdx)
// MODE 2: proj v (plain A=Wv, B=Mt; bias by row; bf16 out [b][c][p])
// MODE 3: av (plain A=V, B=att; gamma*acc bf16 out rows stride HW)
template<int MODE>
__global__ __launch_bounds__(256) void gemm_nt(
    const char* __restrict__ Aq, const char* __restrict__ Bq,
    const float* __restrict__ bias, const float* __restrict__ gammap,
    float* __restrict__ outFa, float* __restrict__ outFb,
    u16* __restrict__ outUa, u16* __restrict__ outUb)
{
  constexpr int NTl = (MODE <= 1) ? 8 : (MODE == 2 ? 4 : 2);
  __shared__ __align__(16) u16 smem[34048];   // 2 ring bufs of 17024 u16; epilogue fp32 [128][132]

  const int t    = threadIdx.x;
  const int lane = t & 63;
  const int wid  = t >> 6;
  const int wr   = (wid >> 1) << 6;
  const int wc   = (wid & 1) << 6;

  long abase = 0, bbase = 0, ars = 0, brs = 0;
  int b = 0, m0 = 0, n0 = 0, xx = 0, ct = 0, dir = 0, sOut = 0;

  if constexpr (MODE == 0) {
    b = blockIdx.z; m0 = blockIdx.x << 7; n0 = blockIdx.y << 7;
    abase = ((long)b * HW_ + m0) * 1024; ars = 1024;
    bbase = (long)n0 * 1024;             brs = 1024;
  } else if constexpr (MODE == 1) {
    int bid = blockIdx.x;
    b = bid >> 8; dir = (bid >> 7) & 1; xx = bid & 127;
    sOut = b * 128 + xx;
    if (dir) { abase = (long)b * 16777216L + (long)xx * 1024; ars = 131072; }
    else     { abase = (long)b * 16777216L + (long)xx * 131072; ars = 1024; }
    bbase = abase; brs = ars;
  } else if constexpr (MODE == 2) {
    b = blockIdx.z; m0 = blockIdx.y << 7; n0 = blockIdx.x << 7;
    abase = (long)m0 * 512;              ars = 512;
    bbase = ((long)b * HW_ + n0) * 512;  brs = 512;
  } else {
    int s = blockIdx.x; ct = blockIdx.y; b = s >> 7; xx = s & 127;
    sOut = s;
    abase = ((long)b * 256 + (long)(ct << 7)) * 32768L + (long)xx * 256; ars = 32768;
    bbase = (long)s * 32768L; brs = 256;
  }

  const char* pA = Aq + abase;
  const char* pB = Bq + bbase;

  f32x4 acc[4][4];
  for (int i = 0; i < 4; i++)
    for (int j = 0; j < 4; j++)
      acc[i][j] = (f32x4){0.f, 0.f, 0.f, 0.f};

  auto stage = [&](int buf, int kt) {
    u16* T1 = smem + buf * 17024;
    u16* T2 = T1 + 8192;
    const long ko = (long)kt * 128;
    #pragma unroll
    for (int i = 0; i < 4; i++) {
      int r = (i << 5) + (t >> 3);
      int c = (t & 7) ^ (r & 7);
      GLDS(pA + (long)r * ars + ko + (c << 4), T1 + (i << 11) + ((t >> 6) << 9));
      GLDS(pB + (long)r * brs + ko + (c << 4), T2 + (i << 11) + ((t >> 6) << 9));
    }
  };

  const int khi = lane >> 4;
  const int rl  = lane & 15;

  stage(0, 0);
  stage(1, 1);

  #pragma unroll
  for (int kt = 0; kt < NTl; ++kt) {
    if (kt + 1 < NTl) asm volatile("s_waitcnt vmcnt(8)" ::: "memory");
    else              asm volatile("s_waitcnt vmcnt(0)" ::: "memory");
    __builtin_amdgcn_sched_barrier(0);
    __builtin_amdgcn_s_barrier();
    __builtin_amdgcn_sched_barrier(0);

    const u16* T1 = smem + (kt & 1) * 17024;
    const u16* T2 = T1 + 8192;

    short8 fa0[4], fa1[4], fb0[4], fb1[4];
    #pragma unroll
    for (int f = 0; f < 4; f++) {
      fa0[f] = *frg(T1, wr + f * 16 + rl, khi);
      fa1[f] = *frg(T1, wr + f * 16 + rl, 4 + khi);
      fb0[f] = *frg(T2, wc + f * 16 + rl, khi);
      fb1[f] = *frg(T2, wc + f * 16 + rl, 4 + khi);
    }

    __builtin_amdgcn_s_setprio(1);
    #pragma unroll
    for (int fm = 0; fm < 4; fm++) {
      #pragma unroll
      for (int fn = 0; fn < 4; fn++) {
        if constexpr (MODE <= 1) {
          // split: hi*hi + hi*lo + lo*hi
          acc[fm][fn] = __builtin_amdgcn_mfma_f32_16x16x32_bf16(fa0[fm], fb0[fn], acc[fm][fn], 0, 0, 0);
          acc[fm][fn] = __builtin_amdgcn_mfma_f32_16x16x32_bf16(fa0[fm], fb1[fn], acc[fm][fn], 0, 0, 0);
          acc[fm][fn] = __builtin_amdgcn_mfma_f32_16x16x32_bf16(fa1[fm], fb0[fn], acc[fm][fn], 0, 0, 0);
        } else {
          // plain BK=64: two k-halves
          acc[fm][fn] = __builtin_amdgcn_mfma_f32_16x16x32_bf16(fa0[fm], fb0[fn], acc[fm][fn], 0, 0, 0);
          acc[fm][fn] = __builtin_amdgcn_mfma_f32_16x16x32_bf16(fa1[fm], fb1[fn], acc[fm][fn], 0, 0, 0);
        }
      }
    }
    __builtin_amdgcn_s_setprio(0);

    __builtin_amdgcn_s_barrier();
    __builtin_amdgcn_sched_barrier(0);
    if (kt + 2 < NTl) stage(kt & 1, kt + 2);
  }

  // ---------- epilogue: fragments -> LDS fp32 [128][132] -> wide coalesced stores ----------
  float gma = 0.f;
  if constexpr (MODE == 3) gma = gammap[0];
  float* LDSE = (float*)smem;

  #pragma unroll
  for (int fm = 0; fm < 4; fm++) {
    #pragma unroll
    for (int fn = 0; fn < 4; fn++) {
      #pragma unroll
      for (int r = 0; r < 4; r++) {
        int lr = wr + fm * 16 + ((lane >> 4) << 2) + r;
        int lc = wc + fn * 16 + rl;
        float v = acc[fm][fn][r];
        if constexpr (MODE == 0) v += bias[n0 + lc];
        if constexpr (MODE == 2) v += bias[m0 + lr];
        if constexpr (MODE == 3) v *= gma;
        LDSE[lr * 132 + lc] = v;
      }
    }
  }
  __syncthreads();

  if constexpr (MODE == 0) {
    u16* outp = (n0 < 256) ? outUa : outUb;
    long rowb = ((long)b * HW_ + m0) * 512;   // u16 units, row = 512 u16
    int cbu = (n0 & 255) * 2;                  // u16 offset of this 128-col half
    #pragma unroll
    for (int k = 0; k < 16; ++k) {
      int row = k * 8 + (t >> 5);
      int iu  = (t & 31) * 8;                  // u16 offset within 256-u16 piece
      int off = iu & 63;
      int lcol = (iu >> 6) * 32 + (off & 31);
      const float* src = &LDSE[row * 132 + lcol];
      u16 o[8];
      if (off < 32) {
        #pragma unroll
        for (int j = 0; j < 8; j++) o[j] = f2bf(src[j]);
      } else {
        #pragma unroll
        for (int j = 0; j < 8; j++) { float v = src[j]; u16 h = f2bf(v); o[j] = f2bf(v - bf2f(h)); }
      }
      *(short8*)(outp + rowb + (long)row * 512 + cbu + iu) = *(short8*)o;
    }
  } else if constexpr (MODE == 1) {
    float* op = dir ? outFb : outFa;
    long ob = (long)sOut * 16384;
    #pragma unroll
    for (int k = 0; k < 16; ++k) {
      int row = k * 8 + (t >> 5);
      int c4 = (t & 31) * 4;
      f32x4 v = *(const f32x4*)&LDSE[row * 132 + c4];
      *(f32x4*)(op + ob + (long)row * 128 + c4) = v;
    }
  } else {
    #pragma unroll
    for (int k = 0; k < 8; ++k) {
      int row = k * 16 + (t >> 4);
      int c8 = (t & 15) * 8;
      const float* src = &LDSE[row * 132 + c8];
      u16 o[8];
      #pragma unroll
      for (int j = 0; j < 8; j++) o[j] = f2bf(src[j]);
      long addr;
      if constexpr (MODE == 2) addr = ((long)b * 256 + m0 + row) * HW_ + n0 + c8;
      else                     addr = ((long)b * 256 + (ct << 7) + row) * HW_ + (long)xx * 128 + c8;
      *(short8*)(outUa + addr) = *(short8*)o;
    }
  }
}

// ---------------- fused: edge -> interleaved split bf16 [p][c], mask -> plain bf16 [p][c] ----
__global__ __launch_bounds__(256) void split_transpose2(const float* __restrict__ edge,
    const float* __restrict__ mask, u16* __restrict__ Xs, u16* __restrict__ Mt)
{
  int b = blockIdx.z, c0 = blockIdx.y << 5, p0 = blockIdx.x << 5;
  __shared__ float tileE[32][33];
  __shared__ float tileM[32][33];
  int tx = threadIdx.x, ty = threadIdx.y;
  const float* E = edge + (long)b * CHW_;
  const float* M = mask + (long)b * CHW_;
  #pragma unroll
  for (int r = 0; r < 4; r++) {
    int cc = ty + (r << 3);
    long g = (long)(c0 + cc) * HW_ + p0 + tx;
    tileE[cc][tx] = E[g];
    tileM[cc][tx] = M[g];
  }
  __syncthreads();
  int blk = (c0 >> 5) * 64;
  #pragma unroll
  for (int r = 0; r < 4; r++) {
    int pp = ty + (r << 3);
    long prow = (long)b * HW_ + p0 + pp;
    float x = tileE[tx][pp];
    u16 h = f2bf(x);
    Xs[prow * 512 + blk + tx]      = h;
    Xs[prow * 512 + blk + 32 + tx] = f2bf(x - bf2f(h));
    Mt[prow * 256 + c0 + tx]       = f2bf(tileM[tx][pp]);
  }
}

// ---------------- weight prep: Wcat=[Wq;Wk] interleaved split, Wv plain, bias cat ----------
__global__ __launch_bounds__(256) void wsplit(const float* __restrict__ Wq,
    const float* __restrict__ Wk, const float* __restrict__ Wv,
    const float* __restrict__ bq, const float* __restrict__ bk,
    u16* Wc, u16* Wvp, float* bcat)
{
  int i = blockIdx.x * 256 + threadIdx.x;
  int o = i >> 8, c = i & 255;
  long pos = (long)o * 512 + (c >> 5) * 64 + (c & 31);
  float q = Wq[i]; u16 a = f2bf(q); Wc[pos] = a; Wc[pos + 32] = f2bf(q - bf2f(a));
  float k = Wk[i]; u16 d = f2bf(k);
  Wc[pos + 131072] = d; Wc[pos + 131072 + 32] = f2bf(k - bf2f(d));
  Wvp[i] = f2bf(Wv[i]);
  if (blockIdx.x == 0) {
    bcat[threadIdx.x]       = bq[threadIdx.x];
    bcat[256 + threadIdx.x] = bk[threadIdx.x];
  }
}

// ---------------- bf16 H<->W transpose: dst[bc][w*128+h] = src[bc][h*128+w] ----------------
__global__ __launch_bounds__(256) void transpose_hw_bf16(const u16* __restrict__ src,
                                                         u16* __restrict__ dst)
{
  int bc = blockIdx.z;
  int h0 = blockIdx.x << 5, w0 = blockIdx.y << 5;
  long base = (long)bc * HW_;
  __shared__ u16 tile[32][34];
  int tx = threadIdx.x, ty = threadIdx.y;
  #pragma unroll
  for (int r = 0; r < 4; r++)
    tile[ty + (r << 3)][tx] = src[base + (long)(h0 + ty + (r << 3)) * 128 + w0 + tx];
  __syncthreads();
  #pragma unroll
  for (int r = 0; r < 4; r++) {
    int ww = ty + (r << 3);
    dst[base + (long)(w0 + ww) * 128 + h0 + tx] = tile[tx][ww];
  }
}

// ---------------- softmax over concat(rowH[128], rowW[128]) + bf16 copies, vectorized ------
__global__ __launch_bounds__(256) void softmax_kernel(float* __restrict__ attH,
    float* __restrict__ attW, u16* __restrict__ aHb, u16* __restrict__ aWb)
{
  int g  = threadIdx.x & 31;                     // 32 lanes per row
  long r = (long)blockIdx.x * 8 + (threadIdx.x >> 5);
  int b = (int)(r >> 14);
  int h = (int)((r >> 7) & 127);
  int w = (int)(r & 127);
  long baseH = ((long)(b * 128 + w) * 128 + h) * 128;
  long baseW = r * 128;
  float* rp = (g < 16) ? (attH + baseH) : (attW + baseW);
  u16*   up = (g < 16) ? (aHb + baseH)  : (aWb + baseW);
  int j0 = (g & 15) * 8;
  f32x4 v0 = *(f32x4*)(rp + j0);
  f32x4 v1 = *(f32x4*)(rp + j0 + 4);
  float m = fmaxf(fmaxf(fmaxf(v0.x, v0.y), fmaxf(v0.z, v0.w)),
                  fmaxf(fmaxf(v1.x, v1.y), fmaxf(v1.z, v1.w)));
  #pragma unroll
  for (int off = 16; off; off >>= 1) m = fmaxf(m, __shfl_xor(m, off, 32));
  float e[8];
  e[0]=expf(v0.x-m); e[1]=expf(v0.y-m); e[2]=expf(v0.z-m); e[3]=expf(v0.w-m);
  e[4]=expf(v1.x-m); e[5]=expf(v1.y-m); e[6]=expf(v1.z-m); e[7]=expf(v1.w-m);
  float s = ((e[0]+e[1])+(e[2]+e[3])) + ((e[4]+e[5])+(e[6]+e[7]));
  #pragma unroll
  for (int off = 16; off; off >>= 1) s += __shfl_xor(s, off, 32);
  float inv = 1.0f / s;
  #pragma unroll
  for (int j = 0; j < 8; j++) e[j] *= inv;
  *(f32x4*)(rp + j0)     = (f32x4){e[0], e[1], e[2], e[3]};
  *(f32x4*)(rp + j0 + 4) = (f32x4){e[4], e[5], e[6], e[7]};
  u16 o[8];
  #pragma unroll
  for (int j = 0; j < 8; j++) o[j] = f2bf(e[j]);
  *(short8*)(up + j0) = *(short8*)o;
}

// ---------------- merge: out = pW + tmp^T + mask ----------------
__global__ __launch_bounds__(256) void merge_kernel(const u16* __restrict__ tmp,
    const u16* __restrict__ pW, const float* __restrict__ mask, float* __restrict__ out)
{
  int bc = blockIdx.z;
  int h0 = blockIdx.x << 5, w0 = blockIdx.y << 5;
  long base = (long)bc * HW_;
  __shared__ u16 tile[32][33];
  int tx = threadIdx.x, ty = threadIdx.y;
  #pragma unroll
  for (int r = 0; r < 4; r++) {
    int ww = ty + (r << 3);
    tile[ww][tx] = tmp[base + (long)(w0 + ww) * 128 + h0 + tx];
  }
  __syncthreads();
  #pragma unroll
  for (int r = 0; r < 4; r++) {
    int hh = ty + (r << 3);
    long o = base + (long)(h0 + hh) * 128 + w0 + tx;
    out[o] = bf2f(pW[o]) + bf2f(tile[tx][hh]) + mask[o];
  }
}

extern "C" void kernel_launch(void* const* d_in, const int* in_sizes, int n_in,
                              void* d_out, int out_size, void* d_ws, size_t ws_size,
                              hipStream_t stream) {
  const float* edge  = (const float*)d_in[0];
  const float* mask  = (const float*)d_in[1];
  const float* Wq    = (const float*)d_in[2];
  const float* bq    = (const float*)d_in[3];
  const float* Wk    = (const float*)d_in[4];
  const float* bk    = (const float*)d_in[5];
  const float* Wv    = (const float*)d_in[6];
  const float* bv    = (const float*)d_in[7];
  const float* gamma = (const float*)d_in[8];

  float* out  = (float*)d_out;
  float* attH = out + NT;            // B*W*H*H
  float* attW = attH + 16777216L;    // B*H*W*W

  char* W = (char*)d_ws;
  u16* Xs  = (u16*)(W);                    // 128 MiB interleaved split X [b][p][512]
  u16* Mt  = (u16*)(W + 134217728L);       // 64 MiB plain bf16 mask^T [b][p][256]
  u16* Qs  = (u16*)(W + 201326592L);       // 128 MiB
  u16* Ks  = (u16*)(W + 335544320L);       // 128 MiB
  u16* Vb  = (u16*)(W + 469762048L);       // 64 MiB
  u16* Wc  = (u16*)(W + 536870912L);       // 512 KiB Wcat interleaved
  u16* Wvp = Wc + 262144;                  // 128 KiB
  float* bcat = (float*)(Wvp + 65536);
  // reuses
  u16* Vtb = (u16*)(W);                    // over Xs (dead after proj qk)
  u16* aWb = (u16*)(W + 67108864L);        // over Xs upper half
  u16* aHb = (u16*)(W + 100663296L);
  u16* tmp = (u16*)(W + 201326592L);       // over Qs (dead after energy)
  u16* pW  = (u16*)(W + 335544320L);       // over Ks

  dim3 tb(32, 8);

  wsplit<<<256, 256, 0, stream>>>(Wq, Wk, Wv, bq, bk, Wc, Wvp, bcat);
  split_transpose2<<<dim3(512, 8, 8), tb, 0, stream>>>(edge, mask, Xs, Mt);

  gemm_nt<0><<<dim3(128, 4, 8), 256, 0, stream>>>(
      (const char*)Xs, (const char*)Wc, bcat, nullptr, nullptr, nullptr, Qs, Ks);
  gemm_nt<2><<<dim3(128, 2, 8), 256, 0, stream>>>(
      (const char*)Wvp, (const char*)Mt, bv, nullptr, nullptr, nullptr, Vb, nullptr);

  transpose_hw_bf16<<<dim3(4, 4, 2048), tb, 0, stream>>>(Vb, Vtb);

  gemm_nt<1><<<dim3(2048), 256, 0, stream>>>(
      (const char*)Qs, (const char*)Ks, nullptr, nullptr, attW, attH, nullptr, nullptr);

  softmax_kernel<<<dim3(16384), 256, 0, stream>>>(attH, attW, aHb, aWb);

  gemm_nt<3><<<dim3(1024, 2), 256, 0, stream>>>(
      (const char*)Vtb, (const char*)aHb, nullptr, gamma, nullptr, nullptr, tmp, nullptr);
  gemm_nt<3><<<dim3(1024, 2), 256, 0, stream>>>(
      (const char*)Vb, (const char*)aWb, nullptr, gamma, nullptr, nullptr, pW, nullptr);

  merge_kernel<<<dim3(4, 4, 2048), tb, 0, stream>>>(tmp, pW, mask, out);
}